// Round 16
// baseline (1015.417 us; speedup 1.0000x reference)
//
#include <hip/hip_runtime.h>
#include <hip/hip_bf16.h>

using bf16 = __hip_bfloat16;
typedef __attribute__((ext_vector_type(8))) short bf16x8;
typedef __attribute__((ext_vector_type(4))) float f32x4;

constexpr int N_   = 16384;
constexpr int E_   = 262144;
constexpr int F_   = 16;
constexpr int H_   = 128;
constexpr int NF1_ = 640;    // z(512) | skip(128)
constexpr int DFF_ = 512;
constexpr int G_   = 128;
constexpr int L_   = 5;
constexpr float EPS_ = 1e-5f;

constexpr int WCAT1SZ = NF1_ * 128;    // 81920
constexpr int W1TSZ   = 512 * 128;
constexpr int W2TSZ   = 512 * 128;
constexpr int WVSSZ   = 128 * 512;     // Wvs: [128 n][512 k]
constexpr int TRBLKS  = 5 * 144;       // Ws:16 + W1:64 + W2:64 per layer

__device__ __forceinline__ float gelu_f(float x) {
  return 0.5f * x * (1.0f + erff(x * 0.70710678118654752440f));
}

__device__ __forceinline__ void unpack8(const uint4 w, float* f) {
  f[0] = __uint_as_float(w.x << 16); f[1] = __uint_as_float(w.x & 0xFFFF0000u);
  f[2] = __uint_as_float(w.y << 16); f[3] = __uint_as_float(w.y & 0xFFFF0000u);
  f[4] = __uint_as_float(w.z << 16); f[5] = __uint_as_float(w.z & 0xFFFF0000u);
  f[6] = __uint_as_float(w.w << 16); f[7] = __uint_as_float(w.w & 0xFFFF0000u);
}

// ---------------- weight prep: transposes (Ws,W1,W2) + bias tails ----------------
__global__ __launch_bounds__(256) void k_ptrans(
    const float* __restrict__ Ws, const float* __restrict__ W1,
    const float* __restrict__ W2, const float* __restrict__ bs,
    const float* __restrict__ bv,
    bf16* __restrict__ Wcat1, bf16* __restrict__ W1t, bf16* __restrict__ W2t,
    float* __restrict__ bcat, float* __restrict__ bvm) {
  __shared__ float lds[32][33];
  const int b = blockIdx.x;
  if (b >= TRBLKS) {                 // tails: bcat skip-cols + bvm
    int j = (b - TRBLKS) * 256 + threadIdx.x;
    if (j < 5 * NF1_) {
      int l = j / NF1_, c = j % NF1_;
      if (c >= 512) bcat[j] = bs[l * 128 + (c - 512)];
    } else if (j < 5 * NF1_ + 5 * 128) {
      int j2 = j - 5 * NF1_;
      int l = j2 / 128, n = j2 % 128;
      bvm[j2] = 0.25f * (bv[l * 512 + n] + bv[l * 512 + 128 + n]
                       + bv[l * 512 + 256 + n] + bv[l * 512 + 384 + n]);
    }
    return;
  }
  const int l = b / 144, t = b % 144;
  const float* src; int C; bf16* dst; int dld; int nof; int tt;
  if (t < 16) {         // Ws: [128][128] -> Wcat1 rows 512..639
    tt = t;
    src = Ws + (size_t)l * 128 * 128; C = 128;
    dst = Wcat1 + (size_t)l * WCAT1SZ; dld = 128; nof = 512;
  } else if (t < 80) {  // W1
    tt = t - 16;
    src = W1 + (size_t)l * 128 * 512; C = 512;
    dst = W1t + (size_t)l * W1TSZ; dld = 128; nof = 0;
  } else {              // W2
    tt = t - 80;
    src = W2 + (size_t)l * 512 * 128; C = 128;
    dst = W2t + (size_t)l * W2TSZ; dld = 512; nof = 0;
  }
  const int tpr = C >> 5;
  const int r0 = (tt / tpr) * 32, c0 = (tt % tpr) * 32;
  const int j = threadIdx.x & 31, g = threadIdx.x >> 5;
#pragma unroll
  for (int ii = 0; ii < 4; ++ii) {
    int i = g * 4 + ii;
    lds[i][j] = src[(size_t)(r0 + i) * C + c0 + j];
  }
  __syncthreads();
#pragma unroll
  for (int ii = 0; ii < 4; ++ii) {
    int i = g * 4 + ii;
    dst[(size_t)(nof + c0 + i) * dld + r0 + j] = __float2bfloat16(lds[j][i]);
  }
}

// ---------------- Wvs: per head, Wvs[n][h*128+c] = 0.25 * Wv[c][h*128+n] ----------------
__global__ __launch_bounds__(256) void k_wvprep(const float* __restrict__ Wv,
                                                bf16* __restrict__ Wvs) {
  __shared__ float lds[32][33];
  const int b = blockIdx.x;            // 5*4*16
  const int l = b / 64, rest = b % 64;
  const int h = rest / 16, tt = rest % 16;
  const int r0 = (tt / 4) * 32, c0 = (tt % 4) * 32;
  const float* src = Wv + (size_t)l * 128 * 512 + h * 128;
  bf16* dst = Wvs + (size_t)l * WVSSZ;
  const int j = threadIdx.x & 31, g = threadIdx.x >> 5;
#pragma unroll
  for (int ii = 0; ii < 4; ++ii) {
    int i = g * 4 + ii;
    lds[i][j] = src[(size_t)(r0 + i) * 512 + c0 + j];
  }
  __syncthreads();
#pragma unroll
  for (int ii = 0; ii < 4; ++ii) {
    int i = g * 4 + ii;
    dst[(size_t)(c0 + i) * 512 + h * 128 + r0 + j] = __float2bfloat16(0.25f * lds[j][i]);
  }
}

// ---------------- G = Wq_h @ Wk_h^T per (layer, head); writes GT rows + z-bias ----------------
__global__ __launch_bounds__(256) void k_gmat(
    const float* __restrict__ Wq, const float* __restrict__ Wk,
    const float* __restrict__ bq,
    bf16* __restrict__ Wcat1, float* __restrict__ bcat) {
  __shared__ float lq[32][132];
  __shared__ float lk[32][132];
  const int l = blockIdx.x >> 2, h = blockIdx.x & 3;
  const int half = blockIdx.y;
  const int tid = threadIdx.x;
  const int c = tid & 127, ch = tid >> 7;
  const int cp0 = half * 64 + ch * 32;
  const float* wqL = Wq + (size_t)l * 128 * 512 + h * 128;
  const float* wkL = Wk + (size_t)l * 128 * 512 + h * 128;
  float acc[32];
#pragma unroll
  for (int j = 0; j < 32; ++j) acc[j] = 0.f;
  for (int a0 = 0; a0 < 128; a0 += 32) {
    __syncthreads();
#pragma unroll
    for (int q4 = 0; q4 < 4; ++q4) {
      int f4 = tid * 4 + q4;
      int row = f4 >> 3, af = f4 & 7;
      float4 gq = *reinterpret_cast<const float4*>(wqL + (size_t)row * 512 + a0 + af * 4);
      float4 gk = *reinterpret_cast<const float4*>(wkL + (size_t)row * 512 + a0 + af * 4);
      lq[af * 4 + 0][row] = gq.x; lq[af * 4 + 1][row] = gq.y;
      lq[af * 4 + 2][row] = gq.z; lq[af * 4 + 3][row] = gq.w;
      lk[af * 4 + 0][row] = gk.x; lk[af * 4 + 1][row] = gk.y;
      lk[af * 4 + 2][row] = gk.z; lk[af * 4 + 3][row] = gk.w;
    }
    __syncthreads();
    for (int a = 0; a < 32; ++a) {
      float wq = lq[a][c];
#pragma unroll
      for (int j = 0; j < 32; ++j) acc[j] = fmaf(wq, lk[a][cp0 + j], acc[j]);
    }
  }
  bf16* gt = Wcat1 + (size_t)l * WCAT1SZ;
#pragma unroll
  for (int j = 0; j < 32; ++j)
    gt[(size_t)(h * 128 + cp0 + j) * 128 + c] = __float2bfloat16(acc[j]);
  if (half == 0 && ch == 0) {
    float s = 0.f;
    const float* wkr = wkL + (size_t)c * 512;
    const float* bqh = bq + (size_t)l * 512 + h * 128;
    for (int a = 0; a < 128; ++a) s = fmaf(wkr[a], bqh[a], s);
    bcat[(size_t)l * NF1_ + h * 128 + c] = s;
  }
}

// ---------------- embedding GEMM + fused BN partial stats ----------------
__global__ __launch_bounds__(256) void k_embed2(const float* __restrict__ x,
    const float* __restrict__ W, const float* __restrict__ b,
    float* __restrict__ out, float* __restrict__ ss, float* __restrict__ sq) {
  __shared__ float xs[128][16];
  __shared__ float wsm[16][128];
  __shared__ float sr[2][128], qr[2][128];
  const int blk = blockIdx.x;
  const int t = threadIdx.x;
  for (int i = t; i < 16 * 128; i += 256) wsm[i >> 7][i & 127] = W[i];
  for (int i = t; i < 128 * 16; i += 256) xs[i >> 4][i & 15] = x[(size_t)blk * 2048 + i];
  __syncthreads();
  const int c = t & 127, rg = t >> 7;
  float bc = b[c];
  float s = 0.f, q = 0.f;
  for (int r = rg * 64; r < rg * 64 + 64; ++r) {
    float v = bc;
#pragma unroll
    for (int f = 0; f < 16; ++f) v = fmaf(xs[r][f], wsm[f][c], v);
    out[(size_t)(blk * 128 + r) * 128 + c] = v;
    s += v; q += v * v;
  }
  sr[rg][c] = s; qr[rg][c] = q;
  __syncthreads();
  if (t < 128) { ss[blk * 128 + t] = sr[0][t] + sr[1][t]; sq[blk * 128 + t] = qr[0][t] + qr[1][t]; }
}

// ---------------- BatchNorm finalize / apply ----------------
template<int NC, int NP>
__global__ void k_bn_finalize(const float* __restrict__ sums, const float* __restrict__ sumsq,
                              const float* __restrict__ g, const float* __restrict__ be,
                              float* __restrict__ a, float* __restrict__ cc) {
  int c = blockIdx.x * 128 + threadIdx.x;
  if (c >= NC) return;
  float s = 0.f, q = 0.f;
  for (int b = 0; b < NP; ++b) { s += sums[(size_t)b * NC + c]; q += sumsq[(size_t)b * NC + c]; }
  float mean = s * (1.0f / N_);
  float var  = q * (1.0f / N_) - mean * mean;
  float inv  = rsqrtf(var + EPS_);
  float aa   = g[c] * inv;
  a[c]  = aa;
  cc[c] = be[c] - aa * mean;
}

template<int NC>
__global__ void k_bn_apply_gelu_cast(const float* __restrict__ xin, const float* __restrict__ a,
                                     const float* __restrict__ cc, bf16* __restrict__ outb) {
  int i4 = (blockIdx.x * 256 + threadIdx.x) * 4;
  int c = i4 & (NC - 1);
  float4 v = *reinterpret_cast<const float4*>(xin + i4);
  union { uint2 u2; bf16 h[4]; } pk;
  pk.h[0] = __float2bfloat16(gelu_f(fmaf(a[c + 0], v.x, cc[c + 0])));
  pk.h[1] = __float2bfloat16(gelu_f(fmaf(a[c + 1], v.y, cc[c + 1])));
  pk.h[2] = __float2bfloat16(gelu_f(fmaf(a[c + 2], v.z, cc[c + 2])));
  pk.h[3] = __float2bfloat16(gelu_f(fmaf(a[c + 3], v.w, cc[c + 3])));
  *reinterpret_cast<uint2*>(outb + i4) = pk.u2;
}

// ---------------- CSR build over dst ----------------
__global__ void k_count(const int* __restrict__ dst, int* __restrict__ deg) {
  int e = blockIdx.x * 256 + threadIdx.x;
  if (e < E_) atomicAdd(&deg[dst[e]], 1);
}

__global__ void k_bsum(const int* __restrict__ deg, int* __restrict__ bsum) {
  __shared__ int sh[256];
  int t = threadIdx.x;
  sh[t] = deg[blockIdx.x * 256 + t];
  __syncthreads();
  for (int d = 128; d > 0; d >>= 1) { if (t < d) sh[t] += sh[t + d]; __syncthreads(); }
  if (t == 0) bsum[blockIdx.x] = sh[0];
}

__global__ void k_boffs(const int* __restrict__ deg, const int* __restrict__ bsum,
                        int* __restrict__ offs) {
  __shared__ int sh[256];
  __shared__ int baseSh;
  int t = threadIdx.x;
  if (t < 64) {
    int v = bsum[t];
    int s = v;
    for (int d = 1; d < 64; d <<= 1) { int o = __shfl_up(s, d); if (t >= d) s += o; }
    if (t == (int)blockIdx.x) baseSh = s - v;
  }
  int v = deg[blockIdx.x * 256 + t];
  sh[t] = v;
  __syncthreads();
  for (int d = 1; d < 256; d <<= 1) {
    int add = (t >= d) ? sh[t - d] : 0;
    __syncthreads();
    sh[t] += add;
    __syncthreads();
  }
  offs[blockIdx.x * 256 + t] = baseSh + sh[t] - v;
  if (blockIdx.x == 63 && t == 255) offs[N_] = E_;
}

__global__ void k_scatter(const int* __restrict__ src, const int* __restrict__ dst,
                          const int* __restrict__ off, int* __restrict__ cursor,
                          int* __restrict__ srcs) {
  int e = blockIdx.x * 256 + threadIdx.x;
  if (e < E_) {
    int d = dst[e];
    int pos = off[d] + atomicAdd(&cursor[d], 1);
    srcs[pos] = src[e];
  }
}

// ---------------- block MFMA GEMM (K=128), FFN1 path (needs BN stats) ----------------
// MODE 3: NOUT=512: fp32 out + per-m-tile BN column partials; +bias. grid (N/128, 4)
template<int KDIM, int NOUT, int TM, int MODE>
__global__ __launch_bounds__(256) void k_mfma(
    const bf16* __restrict__ A, const bf16* __restrict__ BT,
    const float* __restrict__ bias,
    float* __restrict__ outF,
    float* __restrict__ ss, float* __restrict__ sq) {
  constexpr int MF = TM / 32;
  __shared__ bf16 As[TM][72];
  __shared__ bf16 Bs[128][72];
  __shared__ float sred[2][128], qred[2][128];
  const int tid = threadIdx.x;
  const int wid = tid >> 6, lane = tid & 63;
  const int wr = wid >> 1, wc = wid & 1;
  const int m0 = blockIdx.x * TM, n0 = blockIdx.y * 128;
  const int ln = lane & 15, lq = lane >> 4;
  f32x4 acc[MF][4];
#pragma unroll
  for (int i = 0; i < MF; ++i)
#pragma unroll
    for (int j = 0; j < 4; ++j) acc[i][j] = (f32x4){0.f, 0.f, 0.f, 0.f};

  for (int k0 = 0; k0 < KDIM; k0 += 64) {
#pragma unroll
    for (int u = tid; u < TM * 8; u += 256) {
      int r = u >> 3, c = u & 7;
      *(uint4*)(&As[r][c * 8]) = *(const uint4*)(A + (size_t)(m0 + r) * KDIM + k0 + c * 8);
    }
#pragma unroll
    for (int u = tid; u < 1024; u += 256) {
      int r = u >> 3, c = u & 7;
      *(uint4*)(&Bs[r][c * 8]) = *(const uint4*)(BT + (size_t)(n0 + r) * KDIM + k0 + c * 8);
    }
    __syncthreads();
#pragma unroll
    for (int kk = 0; kk < 2; ++kk) {
      bf16x8 af[MF], bg[4];
#pragma unroll
      for (int i = 0; i < MF; ++i)
        af[i] = *(const bf16x8*)(&As[wr * (TM / 2) + i * 16 + ln][kk * 32 + lq * 8]);
#pragma unroll
      for (int j = 0; j < 4; ++j)
        bg[j] = *(const bf16x8*)(&Bs[wc * 64 + j * 16 + ln][kk * 32 + lq * 8]);
#pragma unroll
      for (int i = 0; i < MF; ++i)
#pragma unroll
        for (int j = 0; j < 4; ++j)
          acc[i][j] = __builtin_amdgcn_mfma_f32_16x16x32_bf16(af[i], bg[j], acc[i][j], 0, 0, 0);
    }
    __syncthreads();
  }
  float ssj[4] = {0.f, 0.f, 0.f, 0.f}, sqj[4] = {0.f, 0.f, 0.f, 0.f};
#pragma unroll
  for (int i = 0; i < MF; ++i) {
#pragma unroll
    for (int j = 0; j < 4; ++j) {
      int gcol = n0 + wc * 64 + j * 16 + ln;
      float bv = bias[gcol];
      int row0 = m0 + wr * (TM / 2) + i * 16 + lq * 4;
#pragma unroll
      for (int qq = 0; qq < 4; ++qq) {
        float val = acc[i][j][qq] + bv;
        int row = row0 + qq;
        outF[(size_t)row * NOUT + gcol] = val;
        ssj[j] += val; sqj[j] += val * val;
      }
    }
  }
#pragma unroll
  for (int j = 0; j < 4; ++j) {
    ssj[j] += __shfl_xor(ssj[j], 16); ssj[j] += __shfl_xor(ssj[j], 32);
    sqj[j] += __shfl_xor(sqj[j], 16); sqj[j] += __shfl_xor(sqj[j], 32);
  }
  if (lq == 0) {
#pragma unroll
    for (int j = 0; j < 4; ++j) {
      sred[wr][wc * 64 + j * 16 + ln] = ssj[j];
      qred[wr][wc * 64 + j * 16 + ln] = sqj[j];
    }
  }
  __syncthreads();
  if (tid < 128) {
    ss[(size_t)blockIdx.x * NOUT + n0 + tid] = sred[0][tid] + sred[1][tid];
    sq[(size_t)blockIdx.x * NOUT + n0 + tid] = qred[0][tid] + qred[1][tid];
  }
}

// ---------------- skinny GEMM: B resident in LDS (fragment-major), barrier-free main loop ----
// grid (N/64, CSPL): blockIdx.y = column chunk.
// MODE 2: K=128, A bf16: route z fp32 (col<512) / xr fp32; +bias.
// MODE 5: K=512, A bf16: fp32 out, no bias.
// MODE 7: K=512, A fp32 pre-BN: staging applies BN(aS,cS)+GELU, casts bf16; fp32+bf16 out; +bias.
template<int KDIM, int NOUT, int CSPL, int MODE>
__global__ __launch_bounds__(256) void k_sgemm(
    const bf16* __restrict__ A, const float* __restrict__ Af,
    const bf16* __restrict__ BT, const float* __restrict__ bias,
    float* __restrict__ outF, bf16* __restrict__ outB,
    float* __restrict__ zfp, float* __restrict__ xrp,
    const float* __restrict__ aCol, const float* __restrict__ cCol) {
  constexpr int KS = KDIM / 32;            // 4 or 16
  constexpr int NCOL = NOUT / CSPL;
  constexpr int NFR = NCOL / 16;
  __shared__ bf16 Bs[NFR][KS][64][8];      // fragment-major: ds_read linear across lanes
  __shared__ float aS[MODE == 7 ? KDIM : 1], cS[MODE == 7 ? KDIM : 1];
  const int tid = threadIdx.x;
  const int wid = tid >> 6, lane = tid & 63;
  const int ln = lane & 15, lq = lane >> 4;
  const int nc0 = blockIdx.y * NCOL;
  // cooperative fill: coalesced global reads, one-time LDS scatter
  for (int idx = tid; idx < NCOL * (KDIM / 8); idx += 256) {
    int col = idx / (KDIM / 8);
    int oct = idx % (KDIM / 8);
    uint4 w = *(const uint4*)(BT + (size_t)(nc0 + col) * KDIM + oct * 8);
    int ks = oct >> 2, q = oct & 3;
    *(uint4*)(&Bs[col >> 4][ks][q * 16 + (col & 15)][0]) = w;
  }
  if constexpr (MODE == 7) {
    for (int i = tid; i < KDIM; i += 256) { aS[i] = aCol[i]; cS[i] = cCol[i]; }
  }
  __syncthreads();
  const int m0 = blockIdx.x * 64 + wid * 16;
  bf16x8 a[KS];
  if constexpr (MODE == 7) {
    const float* ap = Af + (size_t)(m0 + ln) * KDIM + lq * 8;
#pragma unroll
    for (int ks = 0; ks < KS; ++ks) {
      float4 f0 = *(const float4*)(ap + ks * 32);
      float4 f1 = *(const float4*)(ap + ks * 32 + 4);
      float f[8] = {f0.x, f0.y, f0.z, f0.w, f1.x, f1.y, f1.z, f1.w};
      int colb = lq * 8 + ks * 32;
      union { bf16x8 v; bf16 h[8]; } pk;
#pragma unroll
      for (int j = 0; j < 8; ++j)
        pk.h[j] = __float2bfloat16(gelu_f(fmaf(aS[colb + j], f[j], cS[colb + j])));
      a[ks] = pk.v;
    }
  } else {
    const bf16* ap = A + (size_t)(m0 + ln) * KDIM + lq * 8;
#pragma unroll
    for (int ks = 0; ks < KS; ++ks) a[ks] = *(const bf16x8*)(ap + ks * 32);
  }
  const int orow = m0 + lq * 4;
#pragma unroll
  for (int nf = 0; nf < NFR; ++nf) {
    f32x4 acc0 = (f32x4){0.f, 0.f, 0.f, 0.f};
    f32x4 acc1 = (f32x4){0.f, 0.f, 0.f, 0.f};
#pragma unroll
    for (int ks = 0; ks < KS; ks += 2) {   // two chains -> 2x MFMA ILP
      acc0 = __builtin_amdgcn_mfma_f32_16x16x32_bf16(a[ks],     *(const bf16x8*)(&Bs[nf][ks][lane][0]),     acc0, 0, 0, 0);
      acc1 = __builtin_amdgcn_mfma_f32_16x16x32_bf16(a[ks + 1], *(const bf16x8*)(&Bs[nf][ks + 1][lane][0]), acc1, 0, 0, 0);
    }
    const int col = nc0 + nf * 16 + ln;
    float bv = 0.f;
    if constexpr (MODE != 5) bv = bias[col];
    float v0 = (acc0[0] + acc1[0]) + bv;
    float v1 = (acc0[1] + acc1[1]) + bv;
    float v2 = (acc0[2] + acc1[2]) + bv;
    float v3 = (acc0[3] + acc1[3]) + bv;
    if constexpr (MODE == 2) {
      if (col < 512) {
        zfp[(size_t)(orow + 0) * 512 + col] = v0;
        zfp[(size_t)(orow + 1) * 512 + col] = v1;
        zfp[(size_t)(orow + 2) * 512 + col] = v2;
        zfp[(size_t)(orow + 3) * 512 + col] = v3;
      } else {
        int cx = col - 512;
        xrp[(size_t)(orow + 0) * 128 + cx] = v0;
        xrp[(size_t)(orow + 1) * 128 + cx] = v1;
        xrp[(size_t)(orow + 2) * 128 + cx] = v2;
        xrp[(size_t)(orow + 3) * 128 + cx] = v3;
      }
    } else {
      outF[(size_t)(orow + 0) * NOUT + col] = v0;
      outF[(size_t)(orow + 1) * NOUT + col] = v1;
      outF[(size_t)(orow + 2) * NOUT + col] = v2;
      outF[(size_t)(orow + 3) * NOUT + col] = v3;
      if constexpr (MODE == 7) {
        outB[(size_t)(orow + 0) * NOUT + col] = __float2bfloat16(v0);
        outB[(size_t)(orow + 1) * NOUT + col] = __float2bfloat16(v1);
        outB[(size_t)(orow + 2) * NOUT + col] = __float2bfloat16(v2);
        outB[(size_t)(orow + 3) * NOUT + col] = __float2bfloat16(v3);
      }
    }
  }
}

// ---------------- attention: gather hb only; aggregate hb into per-head agg ----------------
__global__ __launch_bounds__(256) void k_attn(const float* __restrict__ zf,
    const bf16* __restrict__ hb, const int* __restrict__ srcs,
    const int* __restrict__ off, bf16* __restrict__ aggB) {
  const int wave = threadIdx.x >> 6;
  const int lane = threadIdx.x & 63;
  const int bid = blockIdx.x;                      // 4096 blocks
  const int swz = ((bid & 7) << 9) | (bid >> 3);   // XCD-contiguous chunks
  const int node = swz * 4 + wave;
  const int sub = lane & 15;
  const float scale = 0.08838834764831845f;        // 1/sqrt(128)
  float qf[8];
  {
    const float4* qp = reinterpret_cast<const float4*>(zf + (size_t)node * 512) + lane * 2;
    float4 a = qp[0], b = qp[1];
    qf[0]=a.x; qf[1]=a.y; qf[2]=a.z; qf[3]=a.w;
    qf[4]=b.x; qf[5]=b.y; qf[6]=b.z; qf[7]=b.w;
  }
  float m = -1e30f, den = 0.f;
  float acc[8] = {0.f, 0.f, 0.f, 0.f, 0.f, 0.f, 0.f, 0.f};
  const int s0 = off[node], s1 = off[node + 1];
  if (s0 < s1) {
    int i0 = srcs[s0];
    int i1 = (s0 + 1 < s1) ? srcs[s0 + 1] : i0;
    uint4 h0 = *(const uint4*)(hb + (size_t)i0 * 128 + sub * 8);
    uint4 h1 = *(const uint4*)(hb + (size_t)i1 * 128 + sub * 8);
    for (int t = s0; t < s1; t += 2) {
      int j0 = (t + 2 < s1) ? srcs[t + 2] : i0;
      int j1 = (t + 3 < s1) ? srcs[t + 3] : i0;
      uint4 nh0 = *(const uint4*)(hb + (size_t)j0 * 128 + sub * 8);
      uint4 nh1 = *(const uint4*)(hb + (size_t)j1 * 128 + sub * 8);
      {
        float hf[8]; unpack8(h0, hf);
        float p = hf[0]*qf[0]+hf[1]*qf[1]+hf[2]*qf[2]+hf[3]*qf[3]
                + hf[4]*qf[4]+hf[5]*qf[5]+hf[6]*qf[6]+hf[7]*qf[7];
        p += __shfl_xor(p, 1); p += __shfl_xor(p, 2);
        p += __shfl_xor(p, 4); p += __shfl_xor(p, 8);
        float logit = p * scale;
        if (logit > m + 8.f) {
          float co = __expf(m - logit);
          den *= co;
#pragma unroll
          for (int j = 0; j < 8; ++j) acc[j] *= co;
          m = logit;
        }
        float pe = __expf(logit - m);
        den += pe;
#pragma unroll
        for (int j = 0; j < 8; ++j) acc[j] = fmaf(pe, hf[j], acc[j]);
      }
      if (t + 1 < s1) {
        float hf[8]; unpack8(h1, hf);
        float p = hf[0]*qf[0]+hf[1]*qf[1]+hf[2]*qf[2]+hf[3]*qf[3]
                + hf[4]*qf[4]+hf[5]*qf[5]+hf[6]*qf[6]+hf[7]*qf[7];
        p += __shfl_xor(p, 1); p += __shfl_xor(p, 2);
        p += __shfl_xor(p, 4); p += __shfl_xor(p, 8);
        float logit = p * scale;
        if (logit > m + 8.f) {
          float co = __expf(m - logit);
          den *= co;
#pragma unroll
          for (int j = 0; j < 8; ++j) acc[j] *= co;
          m = logit;
        }
        float pe = __expf(logit - m);
        den += pe;
#pragma unroll
        for (int j = 0; j < 8; ++j) acc[j] = fmaf(pe, hf[j], acc[j]);
      }
      h0 = nh0; h1 = nh1;
    }
  }
  float inv = 1.f / (den + 1e-16f);
  union { uint4 u4; bf16 h[8]; } pk;
#pragma unroll
  for (int j = 0; j < 8; ++j) pk.h[j] = __float2bfloat16(acc[j] * inv);
  *reinterpret_cast<uint4*>(aggB + (size_t)node * 512 + lane * 8) = pk.u4;
}

// ---------------- beta gate: out = out0 + bvm (if deg>0); gated = beta*xr + (1-beta)*out ----------------
__global__ __launch_bounds__(256) void k_beta(const float* __restrict__ out0,
    const float* __restrict__ xr, const float* __restrict__ Wb,
    const float* __restrict__ bvm, const int* __restrict__ off,
    bf16* __restrict__ gated) {
  const int wave = threadIdx.x >> 6;
  const int lane = threadIdx.x & 63;
  const int node = blockIdx.x * 4 + wave;
  const int c0 = lane * 2;
  bool hasE = off[node + 1] > off[node];
  const size_t base = (size_t)node * H_ + c0;
  float2 o = *reinterpret_cast<const float2*>(out0 + base);
  if (hasE) { o.x += bvm[c0]; o.y += bvm[c0 + 1]; }
  float2 xv = *reinterpret_cast<const float2*>(xr + base);
  float s = o.x * (Wb[c0] + Wb[256 + c0]) + xv.x * (Wb[128 + c0] - Wb[256 + c0])
          + o.y * (Wb[c0 + 1] + Wb[256 + c0 + 1]) + xv.y * (Wb[128 + c0 + 1] - Wb[256 + c0 + 1]);
#pragma unroll
  for (int d = 1; d < 64; d <<= 1) s += __shfl_xor(s, d);
  float beta = 1.f / (1.f + __expf(-s));
  union { unsigned u; bf16 h[2]; } pk;
  pk.h[0] = __float2bfloat16(beta * xv.x + (1.f - beta) * o.x);
  pk.h[1] = __float2bfloat16(beta * xv.y + (1.f - beta) * o.y);
  *reinterpret_cast<unsigned*>(gated + base) = pk.u;
}

// ---------------- fused segment max-pool + prediction (batch_index sorted) ----------------
__global__ __launch_bounds__(256) void k_poolpred(const float* __restrict__ h,
    const int* __restrict__ batch, const float* __restrict__ predW,
    const float* __restrict__ predb, float* __restrict__ out) {
  __shared__ float cm[2][128];
  __shared__ int range[2];
  const int g = blockIdx.x, t = threadIdx.x;
  if (t < 2) {
    int target = g + t;
    int lo = 0, hi = N_;
    while (lo < hi) { int mid = (lo + hi) >> 1; if (batch[mid] < target) lo = mid + 1; else hi = mid; }
    range[t] = lo;
  }
  __syncthreads();
  const int lo = range[0], hi = range[1];
  const int c = t & 127, rg = t >> 7;
  float m = -3.402823466e+38f;
  for (int r = lo + rg; r < hi; r += 2) m = fmaxf(m, h[(size_t)r * H_ + c]);
  cm[rg][c] = m;
  __syncthreads();
  if (t < 64) {
    float m0 = fmaxf(cm[0][t], cm[1][t]);
    float m1 = fmaxf(cm[0][t + 64], cm[1][t + 64]);
    float s = m0 * predW[t] + m1 * predW[t + 64];
#pragma unroll
    for (int d = 1; d < 64; d <<= 1) s += __shfl_xor(s, d);
    if (t == 0) out[g] = s + predb[0];
  }
}

extern "C" void kernel_launch(void* const* d_in, const int* in_sizes, int n_in,
                              void* d_out, int out_size, void* d_ws, size_t ws_size,
                              hipStream_t stream) {
  const float* x      = (const float*)d_in[0];
  const int*   edge   = (const int*)d_in[1];
  const int*   esrc   = edge;
  const int*   edst   = edge + E_;
  const int*   batch  = (const int*)d_in[2];
  const float* embW   = (const float*)d_in[3];
  const float* embb   = (const float*)d_in[4];
  const float* emb_g  = (const float*)d_in[5];
  const float* emb_be = (const float*)d_in[6];
  const float* Wq     = (const float*)d_in[7];
  const float* bq     = (const float*)d_in[8];
  const float* Wk     = (const float*)d_in[9];
  const float* Wv     = (const float*)d_in[11];
  const float* bv     = (const float*)d_in[12];
  const float* Wskip  = (const float*)d_in[13];
  const float* bskip  = (const float*)d_in[14];
  const float* Wbeta  = (const float*)d_in[15];
  const float* W1     = (const float*)d_in[16];
  const float* b1     = (const float*)d_in[17];
  const float* g1     = (const float*)d_in[18];
  const float* be1    = (const float*)d_in[19];
  const float* W2     = (const float*)d_in[20];
  const float* b2     = (const float*)d_in[21];
  const float* predW  = (const float*)d_in[22];
  const float* predb  = (const float*)d_in[23];

  // ---- workspace layout (aliased lifetimes) ----
  float* ws = (float*)d_ws;
  size_t o = 0;
  auto alloc_f = [&](size_t n) { float* p = ws + o; o += n; return p; };
  float* A32   = alloc_f((size_t)N_ * 512);   // zf (GEMM1->attn) / t1 (FFN1->FFN2)
  float* B32   = alloc_f((size_t)N_ * H_);    // out0 (Vproj->beta) / h32 (FFN2->pool)
  float* xr    = alloc_f((size_t)N_ * H_);
  float* stats = alloc_f((size_t)2 * 128 * DFF_);
  float* a_c   = alloc_f(DFF_);
  float* c_c   = alloc_f(DFF_);
  float* bcat  = alloc_f(5 * NF1_);
  float* bvm   = alloc_f(5 * 128);
  bf16* bp = (bf16*)(ws + o);
  size_t ob = 0;
  auto alloc_b = [&](size_t n) { bf16* p = bp + ob; ob += n; return p; };
  bf16* aggB = alloc_b((size_t)N_ * 512);
  bf16* hb   = alloc_b((size_t)N_ * H_);
  bf16* gated= alloc_b((size_t)N_ * H_);
  bf16* Wcat1= alloc_b((size_t)5 * WCAT1SZ);
  bf16* W1t  = alloc_b((size_t)5 * W1TSZ);
  bf16* W2t  = alloc_b((size_t)5 * W2TSZ);
  bf16* Wvs  = alloc_b((size_t)5 * WVSSZ);
  int* deg    = (int*)(bp + ob);
  int* offs   = deg + N_;
  int* cursor = offs + N_ + 1;
  int* srcs   = cursor + N_;
  int* bsum   = srcs + E_;       // 64

  float* zf   = A32;  float* t1 = A32;
  float* out0 = B32;  float* h32 = B32;

  // ---- weight prep ----
  k_ptrans<<<TRBLKS + 15, 256, 0, stream>>>(Wskip, W1, W2, bskip, bv,
                                            Wcat1, W1t, W2t, bcat, bvm);
  k_wvprep<<<320, 256, 0, stream>>>(Wv, Wvs);
  k_gmat<<<dim3(20, 2), 256, 0, stream>>>(Wq, Wk, bq, Wcat1, bcat);

  // ---- CSR build ----
  hipMemsetAsync(deg, 0, N_ * sizeof(int), stream);
  hipMemsetAsync(cursor, 0, N_ * sizeof(int), stream);
  k_count  <<<E_ / 256, 256, 0, stream>>>(edst, deg);
  k_bsum   <<<64, 256, 0, stream>>>(deg, bsum);
  k_boffs  <<<64, 256, 0, stream>>>(deg, bsum, offs);
  k_scatter<<<E_ / 256, 256, 0, stream>>>(esrc, edst, offs, cursor, srcs);

  // ---- embedding (+fused stats) + BN + GELU -> bf16 ----
  k_embed2<<<128, 256, 0, stream>>>(x, embW, embb, A32, stats, stats + 128 * 128);
  k_bn_finalize<128, 128><<<1, 128, 0, stream>>>(stats, stats + 128 * 128, emb_g, emb_be, a_c, c_c);
  k_bn_apply_gelu_cast<128><<<N_ * H_ / 1024, 256, 0, stream>>>(A32, a_c, c_c, hb);

  for (int l = 0; l < L_; ++l) {
    const float* Wb_ = Wbeta + (size_t)l * 3 * H_;
    const float* b1_ = b1 + (size_t)l * DFF_;
    const float* g1_ = g1 + (size_t)l * DFF_;
    const float* be1_= be1 + (size_t)l * DFF_;
    const float* b2_ = b2 + (size_t)l * H_;

    // GEMM1: z | xr (LDS-B skinny GEMM, K=128, grid 256x5)
    k_sgemm<128, NF1_, 5, 2><<<dim3(N_ / 64, 5), 256, 0, stream>>>(
        hb, nullptr, Wcat1 + (size_t)l * WCAT1SZ, bcat + (size_t)l * NF1_,
        nullptr, nullptr, zf, xr, nullptr, nullptr);

    k_attn<<<N_ / 4, 256, 0, stream>>>(zf, hb, srcs, offs, aggB);

    // Vproj: out0 = aggB @ Wvs (LDS-B skinny GEMM, no bias)
    k_sgemm<512, 128, 2, 5><<<dim3(N_ / 64, 2), 256, 0, stream>>>(
        aggB, nullptr, Wvs + (size_t)l * WVSSZ, nullptr,
        out0, nullptr, nullptr, nullptr, nullptr, nullptr);

    k_beta<<<N_ / 4, 256, 0, stream>>>(out0, xr, Wb_, bvm + (size_t)l * 128, offs, gated);

    // FFN1: t1 = gated @ W1 + b1 (block MFMA) + BN partial stats
    k_mfma<128, 512, 128, 3><<<dim3(N_ / 128, 4), 256, 0, stream>>>(
        gated, W1t + (size_t)l * W1TSZ, b1_, t1, stats, stats + 128 * 512);

    k_bn_finalize<512, 128><<<4, 128, 0, stream>>>(
        stats, stats + 128 * 512, g1_, be1_, a_c, c_c);

    // FFN2: BN+GELU fused into fp32 A-staging (LDS-B skinny GEMM)
    k_sgemm<512, 128, 2, 7><<<dim3(N_ / 64, 2), 256, 0, stream>>>(
        nullptr, t1, W2t + (size_t)l * W2TSZ, b2_,
        h32, hb, nullptr, nullptr, a_c, c_c);
  }

  // ---- fused pooling + prediction ----
  k_poolpred<<<G_, 256, 0, stream>>>(h32, batch, predW, predb, (float*)d_out);
}

// Round 17
// 685.786 us; speedup vs baseline: 1.4807x; 1.4807x over previous
//
#include <hip/hip_runtime.h>
#include <hip/hip_bf16.h>

using bf16 = __hip_bfloat16;
typedef __attribute__((ext_vector_type(8))) short bf16x8;
typedef __attribute__((ext_vector_type(4))) float f32x4;

constexpr int N_   = 16384;
constexpr int E_   = 262144;
constexpr int F_   = 16;
constexpr int H_   = 128;
constexpr int NF1_ = 640;    // z(512) | skip(128)
constexpr int DFF_ = 512;
constexpr int G_   = 128;
constexpr int L_   = 5;
constexpr float EPS_ = 1e-5f;

constexpr int WCAT1SZ = NF1_ * 128;    // 81920
constexpr int W1TSZ   = 512 * 128;
constexpr int W2TSZ   = 512 * 128;
constexpr int WVSSZ   = 128 * 512;     // Wvs: [128 n][512 k]
constexpr int TRBLKS  = 5 * 144;       // Ws:16 + W1:64 + W2:64 per layer

__device__ __forceinline__ float gelu_f(float x) {
  return 0.5f * x * (1.0f + erff(x * 0.70710678118654752440f));
}

__device__ __forceinline__ void unpack8(const uint4 w, float* f) {
  f[0] = __uint_as_float(w.x << 16); f[1] = __uint_as_float(w.x & 0xFFFF0000u);
  f[2] = __uint_as_float(w.y << 16); f[3] = __uint_as_float(w.y & 0xFFFF0000u);
  f[4] = __uint_as_float(w.z << 16); f[5] = __uint_as_float(w.z & 0xFFFF0000u);
  f[6] = __uint_as_float(w.w << 16); f[7] = __uint_as_float(w.w & 0xFFFF0000u);
}

// ---------------- weight prep: transposes (Ws,W1,W2) + bias tails ----------------
__global__ __launch_bounds__(256) void k_ptrans(
    const float* __restrict__ Ws, const float* __restrict__ W1,
    const float* __restrict__ W2, const float* __restrict__ bs,
    const float* __restrict__ bv,
    bf16* __restrict__ Wcat1, bf16* __restrict__ W1t, bf16* __restrict__ W2t,
    float* __restrict__ bcat, float* __restrict__ bvm) {
  __shared__ float lds[32][33];
  const int b = blockIdx.x;
  if (b >= TRBLKS) {                 // tails: bcat skip-cols + bvm
    int j = (b - TRBLKS) * 256 + threadIdx.x;
    if (j < 5 * NF1_) {
      int l = j / NF1_, c = j % NF1_;
      if (c >= 512) bcat[j] = bs[l * 128 + (c - 512)];
    } else if (j < 5 * NF1_ + 5 * 128) {
      int j2 = j - 5 * NF1_;
      int l = j2 / 128, n = j2 % 128;
      bvm[j2] = 0.25f * (bv[l * 512 + n] + bv[l * 512 + 128 + n]
                       + bv[l * 512 + 256 + n] + bv[l * 512 + 384 + n]);
    }
    return;
  }
  const int l = b / 144, t = b % 144;
  const float* src; int C; bf16* dst; int dld; int nof; int tt;
  if (t < 16) {         // Ws: [128][128] -> Wcat1 rows 512..639
    tt = t;
    src = Ws + (size_t)l * 128 * 128; C = 128;
    dst = Wcat1 + (size_t)l * WCAT1SZ; dld = 128; nof = 512;
  } else if (t < 80) {  // W1
    tt = t - 16;
    src = W1 + (size_t)l * 128 * 512; C = 512;
    dst = W1t + (size_t)l * W1TSZ; dld = 128; nof = 0;
  } else {              // W2
    tt = t - 80;
    src = W2 + (size_t)l * 512 * 128; C = 128;
    dst = W2t + (size_t)l * W2TSZ; dld = 512; nof = 0;
  }
  const int tpr = C >> 5;
  const int r0 = (tt / tpr) * 32, c0 = (tt % tpr) * 32;
  const int j = threadIdx.x & 31, g = threadIdx.x >> 5;
#pragma unroll
  for (int ii = 0; ii < 4; ++ii) {
    int i = g * 4 + ii;
    lds[i][j] = src[(size_t)(r0 + i) * C + c0 + j];
  }
  __syncthreads();
#pragma unroll
  for (int ii = 0; ii < 4; ++ii) {
    int i = g * 4 + ii;
    dst[(size_t)(nof + c0 + i) * dld + r0 + j] = __float2bfloat16(lds[j][i]);
  }
}

// ---------------- Wvs: per head, Wvs[n][h*128+c] = 0.25 * Wv[c][h*128+n] ----------------
__global__ __launch_bounds__(256) void k_wvprep(const float* __restrict__ Wv,
                                                bf16* __restrict__ Wvs) {
  __shared__ float lds[32][33];
  const int b = blockIdx.x;            // 5*4*16
  const int l = b / 64, rest = b % 64;
  const int h = rest / 16, tt = rest % 16;
  const int r0 = (tt / 4) * 32, c0 = (tt % 4) * 32;
  const float* src = Wv + (size_t)l * 128 * 512 + h * 128;
  bf16* dst = Wvs + (size_t)l * WVSSZ;
  const int j = threadIdx.x & 31, g = threadIdx.x >> 5;
#pragma unroll
  for (int ii = 0; ii < 4; ++ii) {
    int i = g * 4 + ii;
    lds[i][j] = src[(size_t)(r0 + i) * 512 + c0 + j];
  }
  __syncthreads();
#pragma unroll
  for (int ii = 0; ii < 4; ++ii) {
    int i = g * 4 + ii;
    dst[(size_t)(c0 + i) * 512 + h * 128 + r0 + j] = __float2bfloat16(0.25f * lds[j][i]);
  }
}

// ---------------- G = Wq_h @ Wk_h^T per (layer, head); writes GT rows + z-bias ----------------
__global__ __launch_bounds__(256) void k_gmat(
    const float* __restrict__ Wq, const float* __restrict__ Wk,
    const float* __restrict__ bq,
    bf16* __restrict__ Wcat1, float* __restrict__ bcat) {
  __shared__ float lq[32][132];
  __shared__ float lk[32][132];
  const int l = blockIdx.x >> 2, h = blockIdx.x & 3;
  const int half = blockIdx.y;
  const int tid = threadIdx.x;
  const int c = tid & 127, ch = tid >> 7;
  const int cp0 = half * 64 + ch * 32;
  const float* wqL = Wq + (size_t)l * 128 * 512 + h * 128;
  const float* wkL = Wk + (size_t)l * 128 * 512 + h * 128;
  float acc[32];
#pragma unroll
  for (int j = 0; j < 32; ++j) acc[j] = 0.f;
  for (int a0 = 0; a0 < 128; a0 += 32) {
    __syncthreads();
#pragma unroll
    for (int q4 = 0; q4 < 4; ++q4) {
      int f4 = tid * 4 + q4;
      int row = f4 >> 3, af = f4 & 7;
      float4 gq = *reinterpret_cast<const float4*>(wqL + (size_t)row * 512 + a0 + af * 4);
      float4 gk = *reinterpret_cast<const float4*>(wkL + (size_t)row * 512 + a0 + af * 4);
      lq[af * 4 + 0][row] = gq.x; lq[af * 4 + 1][row] = gq.y;
      lq[af * 4 + 2][row] = gq.z; lq[af * 4 + 3][row] = gq.w;
      lk[af * 4 + 0][row] = gk.x; lk[af * 4 + 1][row] = gk.y;
      lk[af * 4 + 2][row] = gk.z; lk[af * 4 + 3][row] = gk.w;
    }
    __syncthreads();
    for (int a = 0; a < 32; ++a) {
      float wq = lq[a][c];
#pragma unroll
      for (int j = 0; j < 32; ++j) acc[j] = fmaf(wq, lk[a][cp0 + j], acc[j]);
    }
  }
  bf16* gt = Wcat1 + (size_t)l * WCAT1SZ;
#pragma unroll
  for (int j = 0; j < 32; ++j)
    gt[(size_t)(h * 128 + cp0 + j) * 128 + c] = __float2bfloat16(acc[j]);
  if (half == 0 && ch == 0) {
    float s = 0.f;
    const float* wkr = wkL + (size_t)c * 512;
    const float* bqh = bq + (size_t)l * 512 + h * 128;
    for (int a = 0; a < 128; ++a) s = fmaf(wkr[a], bqh[a], s);
    bcat[(size_t)l * NF1_ + h * 128 + c] = s;
  }
}

// ---------------- embedding GEMM + fused BN partial stats ----------------
__global__ __launch_bounds__(256) void k_embed2(const float* __restrict__ x,
    const float* __restrict__ W, const float* __restrict__ b,
    float* __restrict__ out, float* __restrict__ ss, float* __restrict__ sq) {
  __shared__ float xs[128][16];
  __shared__ float wsm[16][128];
  __shared__ float sr[2][128], qr[2][128];
  const int blk = blockIdx.x;
  const int t = threadIdx.x;
  for (int i = t; i < 16 * 128; i += 256) wsm[i >> 7][i & 127] = W[i];
  for (int i = t; i < 128 * 16; i += 256) xs[i >> 4][i & 15] = x[(size_t)blk * 2048 + i];
  __syncthreads();
  const int c = t & 127, rg = t >> 7;
  float bc = b[c];
  float s = 0.f, q = 0.f;
  for (int r = rg * 64; r < rg * 64 + 64; ++r) {
    float v = bc;
#pragma unroll
    for (int f = 0; f < 16; ++f) v = fmaf(xs[r][f], wsm[f][c], v);
    out[(size_t)(blk * 128 + r) * 128 + c] = v;
    s += v; q += v * v;
  }
  sr[rg][c] = s; qr[rg][c] = q;
  __syncthreads();
  if (t < 128) { ss[blk * 128 + t] = sr[0][t] + sr[1][t]; sq[blk * 128 + t] = qr[0][t] + qr[1][t]; }
}

// ---------------- BatchNorm finalize / apply ----------------
template<int NC, int NP>
__global__ void k_bn_finalize(const float* __restrict__ sums, const float* __restrict__ sumsq,
                              const float* __restrict__ g, const float* __restrict__ be,
                              float* __restrict__ a, float* __restrict__ cc) {
  int c = blockIdx.x * 128 + threadIdx.x;
  if (c >= NC) return;
  float s = 0.f, q = 0.f;
  for (int b = 0; b < NP; ++b) { s += sums[(size_t)b * NC + c]; q += sumsq[(size_t)b * NC + c]; }
  float mean = s * (1.0f / N_);
  float var  = q * (1.0f / N_) - mean * mean;
  float inv  = rsqrtf(var + EPS_);
  float aa   = g[c] * inv;
  a[c]  = aa;
  cc[c] = be[c] - aa * mean;
}

template<int NC>
__global__ void k_bn_apply_gelu_cast(const float* __restrict__ xin, const float* __restrict__ a,
                                     const float* __restrict__ cc, bf16* __restrict__ outb) {
  int i4 = (blockIdx.x * 256 + threadIdx.x) * 4;
  int c = i4 & (NC - 1);
  float4 v = *reinterpret_cast<const float4*>(xin + i4);
  union { uint2 u2; bf16 h[4]; } pk;
  pk.h[0] = __float2bfloat16(gelu_f(fmaf(a[c + 0], v.x, cc[c + 0])));
  pk.h[1] = __float2bfloat16(gelu_f(fmaf(a[c + 1], v.y, cc[c + 1])));
  pk.h[2] = __float2bfloat16(gelu_f(fmaf(a[c + 2], v.z, cc[c + 2])));
  pk.h[3] = __float2bfloat16(gelu_f(fmaf(a[c + 3], v.w, cc[c + 3])));
  *reinterpret_cast<uint2*>(outb + i4) = pk.u2;
}

// ---------------- CSR build over dst ----------------
__global__ void k_count(const int* __restrict__ dst, int* __restrict__ deg) {
  int e = blockIdx.x * 256 + threadIdx.x;
  if (e < E_) atomicAdd(&deg[dst[e]], 1);
}

__global__ void k_bsum(const int* __restrict__ deg, int* __restrict__ bsum) {
  __shared__ int sh[256];
  int t = threadIdx.x;
  sh[t] = deg[blockIdx.x * 256 + t];
  __syncthreads();
  for (int d = 128; d > 0; d >>= 1) { if (t < d) sh[t] += sh[t + d]; __syncthreads(); }
  if (t == 0) bsum[blockIdx.x] = sh[0];
}

__global__ void k_boffs(const int* __restrict__ deg, const int* __restrict__ bsum,
                        int* __restrict__ offs) {
  __shared__ int sh[256];
  __shared__ int baseSh;
  int t = threadIdx.x;
  if (t < 64) {
    int v = bsum[t];
    int s = v;
    for (int d = 1; d < 64; d <<= 1) { int o = __shfl_up(s, d); if (t >= d) s += o; }
    if (t == (int)blockIdx.x) baseSh = s - v;
  }
  int v = deg[blockIdx.x * 256 + t];
  sh[t] = v;
  __syncthreads();
  for (int d = 1; d < 256; d <<= 1) {
    int add = (t >= d) ? sh[t - d] : 0;
    __syncthreads();
    sh[t] += add;
    __syncthreads();
  }
  offs[blockIdx.x * 256 + t] = baseSh + sh[t] - v;
  if (blockIdx.x == 63 && t == 255) offs[N_] = E_;
}

__global__ void k_scatter(const int* __restrict__ src, const int* __restrict__ dst,
                          const int* __restrict__ off, int* __restrict__ cursor,
                          int* __restrict__ srcs) {
  int e = blockIdx.x * 256 + threadIdx.x;
  if (e < E_) {
    int d = dst[e];
    int pos = off[d] + atomicAdd(&cursor[d], 1);
    srcs[pos] = src[e];
  }
}

// ---------------- block MFMA GEMM (K=128), round-12 proven ----------------
// MODE 2: NOUT=640: route z fp32 (cols<512) / xr fp32; +bias. grid (N/128, 5)
// MODE 3: NOUT=512: fp32 out + per-m-tile BN column partials; +bias. grid (N/128, 4)
template<int KDIM, int NOUT, int TM, int MODE>
__global__ __launch_bounds__(256) void k_mfma(
    const bf16* __restrict__ A, const bf16* __restrict__ BT,
    const float* __restrict__ bias,
    float* __restrict__ outF,
    float* __restrict__ zfp, float* __restrict__ xrp,
    float* __restrict__ ss, float* __restrict__ sq) {
  constexpr int MF = TM / 32;
  __shared__ bf16 As[TM][72];
  __shared__ bf16 Bs[128][72];
  __shared__ float sred[2][128], qred[2][128];
  const int tid = threadIdx.x;
  const int wid = tid >> 6, lane = tid & 63;
  const int wr = wid >> 1, wc = wid & 1;
  const int m0 = blockIdx.x * TM, n0 = blockIdx.y * 128;
  const int ln = lane & 15, lq = lane >> 4;
  f32x4 acc[MF][4];
#pragma unroll
  for (int i = 0; i < MF; ++i)
#pragma unroll
    for (int j = 0; j < 4; ++j) acc[i][j] = (f32x4){0.f, 0.f, 0.f, 0.f};

  for (int k0 = 0; k0 < KDIM; k0 += 64) {
#pragma unroll
    for (int u = tid; u < TM * 8; u += 256) {
      int r = u >> 3, c = u & 7;
      *(uint4*)(&As[r][c * 8]) = *(const uint4*)(A + (size_t)(m0 + r) * KDIM + k0 + c * 8);
    }
#pragma unroll
    for (int u = tid; u < 1024; u += 256) {
      int r = u >> 3, c = u & 7;
      *(uint4*)(&Bs[r][c * 8]) = *(const uint4*)(BT + (size_t)(n0 + r) * KDIM + k0 + c * 8);
    }
    __syncthreads();
#pragma unroll
    for (int kk = 0; kk < 2; ++kk) {
      bf16x8 af[MF], bg[4];
#pragma unroll
      for (int i = 0; i < MF; ++i)
        af[i] = *(const bf16x8*)(&As[wr * (TM / 2) + i * 16 + ln][kk * 32 + lq * 8]);
#pragma unroll
      for (int j = 0; j < 4; ++j)
        bg[j] = *(const bf16x8*)(&Bs[wc * 64 + j * 16 + ln][kk * 32 + lq * 8]);
#pragma unroll
      for (int i = 0; i < MF; ++i)
#pragma unroll
        for (int j = 0; j < 4; ++j)
          acc[i][j] = __builtin_amdgcn_mfma_f32_16x16x32_bf16(af[i], bg[j], acc[i][j], 0, 0, 0);
    }
    __syncthreads();
  }
  float ssj[4] = {0.f, 0.f, 0.f, 0.f}, sqj[4] = {0.f, 0.f, 0.f, 0.f};
#pragma unroll
  for (int i = 0; i < MF; ++i) {
#pragma unroll
    for (int j = 0; j < 4; ++j) {
      int gcol = n0 + wc * 64 + j * 16 + ln;
      float bv = bias[gcol];
      int row0 = m0 + wr * (TM / 2) + i * 16 + lq * 4;
#pragma unroll
      for (int qq = 0; qq < 4; ++qq) {
        float val = acc[i][j][qq] + bv;
        int row = row0 + qq;
        if (MODE == 3) {
          outF[(size_t)row * NOUT + gcol] = val;
          ssj[j] += val; sqj[j] += val * val;
        } else {
          if (gcol < 512) zfp[(size_t)row * 512 + gcol] = val;
          else            xrp[(size_t)row * H_ + (gcol - 512)] = val;
        }
      }
    }
  }
  if constexpr (MODE == 3) {
#pragma unroll
    for (int j = 0; j < 4; ++j) {
      ssj[j] += __shfl_xor(ssj[j], 16); ssj[j] += __shfl_xor(ssj[j], 32);
      sqj[j] += __shfl_xor(sqj[j], 16); sqj[j] += __shfl_xor(sqj[j], 32);
    }
    if (lq == 0) {
#pragma unroll
      for (int j = 0; j < 4; ++j) {
        sred[wr][wc * 64 + j * 16 + ln] = ssj[j];
        qred[wr][wc * 64 + j * 16 + ln] = sqj[j];
      }
    }
    __syncthreads();
    if (tid < 128) {
      ss[(size_t)blockIdx.x * NOUT + n0 + tid] = sred[0][tid] + sred[1][tid];
      sq[(size_t)blockIdx.x * NOUT + n0 + tid] = qred[0][tid] + qred[1][tid];
    }
  }
}

// ---------------- skinny GEMM: B resident in LDS (fragment-major), barrier-free main loop ----
// C[M,128] = A[M,512] @ BT[128,512]^T. grid (N/64, 2): blockIdx.y = column half.
// MODE 5: fp32 out, no bias. MODE 6: fp32 + bf16 out, +bias.
template<int KDIM, int NOUT, int CSPL, int MODE>
__global__ __launch_bounds__(256) void k_sgemm(
    const bf16* __restrict__ A, const bf16* __restrict__ BT,
    const float* __restrict__ bias,
    float* __restrict__ outF, bf16* __restrict__ outB) {
  constexpr int KS = KDIM / 32;            // 16
  constexpr int NCOL = NOUT / CSPL;        // 64
  constexpr int NFR = NCOL / 16;           // 4
  __shared__ bf16 Bs[NFR][KS][64][8];      // 64 KB, ds_read linear across lanes
  const int tid = threadIdx.x;
  const int wid = tid >> 6, lane = tid & 63;
  const int ln = lane & 15, lq = lane >> 4;
  const int nc0 = blockIdx.y * NCOL;
  // cooperative fill: coalesced global reads, one-time LDS scatter
  for (int idx = tid; idx < NCOL * (KDIM / 8); idx += 256) {
    int col = idx / (KDIM / 8);
    int oct = idx % (KDIM / 8);
    uint4 w = *(const uint4*)(BT + (size_t)(nc0 + col) * KDIM + oct * 8);
    int ks = oct >> 2, q = oct & 3;
    *(uint4*)(&Bs[col >> 4][ks][q * 16 + (col & 15)][0]) = w;
  }
  __syncthreads();
  const int m0 = blockIdx.x * 64 + wid * 16;
  bf16x8 a[KS];
  const bf16* ap = A + (size_t)(m0 + ln) * KDIM + lq * 8;
#pragma unroll
  for (int ks = 0; ks < KS; ++ks) a[ks] = *(const bf16x8*)(ap + ks * 32);
  const int orow = m0 + lq * 4;
#pragma unroll
  for (int nf = 0; nf < NFR; ++nf) {
    f32x4 acc0 = (f32x4){0.f, 0.f, 0.f, 0.f};
    f32x4 acc1 = (f32x4){0.f, 0.f, 0.f, 0.f};
#pragma unroll
    for (int ks = 0; ks < KS; ks += 2) {   // two chains -> 2x MFMA ILP
      acc0 = __builtin_amdgcn_mfma_f32_16x16x32_bf16(a[ks],     *(const bf16x8*)(&Bs[nf][ks][lane][0]),     acc0, 0, 0, 0);
      acc1 = __builtin_amdgcn_mfma_f32_16x16x32_bf16(a[ks + 1], *(const bf16x8*)(&Bs[nf][ks + 1][lane][0]), acc1, 0, 0, 0);
    }
    const int col = nc0 + nf * 16 + ln;
    float bv = 0.f;
    if constexpr (MODE == 6) bv = bias[col];
    float v0 = (acc0[0] + acc1[0]) + bv;
    float v1 = (acc0[1] + acc1[1]) + bv;
    float v2 = (acc0[2] + acc1[2]) + bv;
    float v3 = (acc0[3] + acc1[3]) + bv;
    outF[(size_t)(orow + 0) * NOUT + col] = v0;
    outF[(size_t)(orow + 1) * NOUT + col] = v1;
    outF[(size_t)(orow + 2) * NOUT + col] = v2;
    outF[(size_t)(orow + 3) * NOUT + col] = v3;
    if constexpr (MODE == 6) {
      outB[(size_t)(orow + 0) * NOUT + col] = __float2bfloat16(v0);
      outB[(size_t)(orow + 1) * NOUT + col] = __float2bfloat16(v1);
      outB[(size_t)(orow + 2) * NOUT + col] = __float2bfloat16(v2);
      outB[(size_t)(orow + 3) * NOUT + col] = __float2bfloat16(v3);
    }
  }
}

// ---------------- attention: gather hb only; aggregate hb into per-head agg ----------------
__global__ __launch_bounds__(256) void k_attn(const float* __restrict__ zf,
    const bf16* __restrict__ hb, const int* __restrict__ srcs,
    const int* __restrict__ off, bf16* __restrict__ aggB) {
  const int wave = threadIdx.x >> 6;
  const int lane = threadIdx.x & 63;
  const int bid = blockIdx.x;                      // 4096 blocks
  const int swz = ((bid & 7) << 9) | (bid >> 3);   // XCD-contiguous chunks
  const int node = swz * 4 + wave;
  const int sub = lane & 15;
  const float scale = 0.08838834764831845f;        // 1/sqrt(128)
  float qf[8];
  {
    const float4* qp = reinterpret_cast<const float4*>(zf + (size_t)node * 512) + lane * 2;
    float4 a = qp[0], b = qp[1];
    qf[0]=a.x; qf[1]=a.y; qf[2]=a.z; qf[3]=a.w;
    qf[4]=b.x; qf[5]=b.y; qf[6]=b.z; qf[7]=b.w;
  }
  float m = -1e30f, den = 0.f;
  float acc[8] = {0.f, 0.f, 0.f, 0.f, 0.f, 0.f, 0.f, 0.f};
  const int s0 = off[node], s1 = off[node + 1];
  if (s0 < s1) {
    int i0 = srcs[s0];
    int i1 = (s0 + 1 < s1) ? srcs[s0 + 1] : i0;
    uint4 h0 = *(const uint4*)(hb + (size_t)i0 * 128 + sub * 8);
    uint4 h1 = *(const uint4*)(hb + (size_t)i1 * 128 + sub * 8);
    for (int t = s0; t < s1; t += 2) {
      int j0 = (t + 2 < s1) ? srcs[t + 2] : i0;
      int j1 = (t + 3 < s1) ? srcs[t + 3] : i0;
      uint4 nh0 = *(const uint4*)(hb + (size_t)j0 * 128 + sub * 8);
      uint4 nh1 = *(const uint4*)(hb + (size_t)j1 * 128 + sub * 8);
      {
        float hf[8]; unpack8(h0, hf);
        float p = hf[0]*qf[0]+hf[1]*qf[1]+hf[2]*qf[2]+hf[3]*qf[3]
                + hf[4]*qf[4]+hf[5]*qf[5]+hf[6]*qf[6]+hf[7]*qf[7];
        p += __shfl_xor(p, 1); p += __shfl_xor(p, 2);
        p += __shfl_xor(p, 4); p += __shfl_xor(p, 8);
        float logit = p * scale;
        if (logit > m + 8.f) {
          float co = __expf(m - logit);
          den *= co;
#pragma unroll
          for (int j = 0; j < 8; ++j) acc[j] *= co;
          m = logit;
        }
        float pe = __expf(logit - m);
        den += pe;
#pragma unroll
        for (int j = 0; j < 8; ++j) acc[j] = fmaf(pe, hf[j], acc[j]);
      }
      if (t + 1 < s1) {
        float hf[8]; unpack8(h1, hf);
        float p = hf[0]*qf[0]+hf[1]*qf[1]+hf[2]*qf[2]+hf[3]*qf[3]
                + hf[4]*qf[4]+hf[5]*qf[5]+hf[6]*qf[6]+hf[7]*qf[7];
        p += __shfl_xor(p, 1); p += __shfl_xor(p, 2);
        p += __shfl_xor(p, 4); p += __shfl_xor(p, 8);
        float logit = p * scale;
        if (logit > m + 8.f) {
          float co = __expf(m - logit);
          den *= co;
#pragma unroll
          for (int j = 0; j < 8; ++j) acc[j] *= co;
          m = logit;
        }
        float pe = __expf(logit - m);
        den += pe;
#pragma unroll
        for (int j = 0; j < 8; ++j) acc[j] = fmaf(pe, hf[j], acc[j]);
      }
      h0 = nh0; h1 = nh1;
    }
  }
  float inv = 1.f / (den + 1e-16f);
  union { uint4 u4; bf16 h[8]; } pk;
#pragma unroll
  for (int j = 0; j < 8; ++j) pk.h[j] = __float2bfloat16(acc[j] * inv);
  *reinterpret_cast<uint4*>(aggB + (size_t)node * 512 + lane * 8) = pk.u4;
}

// ---------------- beta gate: out = out0 + bvm (if deg>0); gated = beta*xr + (1-beta)*out ----------------
__global__ __launch_bounds__(256) void k_beta(const float* __restrict__ out0,
    const float* __restrict__ xr, const float* __restrict__ Wb,
    const float* __restrict__ bvm, const int* __restrict__ off,
    bf16* __restrict__ gated) {
  const int wave = threadIdx.x >> 6;
  const int lane = threadIdx.x & 63;
  const int node = blockIdx.x * 4 + wave;
  const int c0 = lane * 2;
  bool hasE = off[node + 1] > off[node];
  const size_t base = (size_t)node * H_ + c0;
  float2 o = *reinterpret_cast<const float2*>(out0 + base);
  if (hasE) { o.x += bvm[c0]; o.y += bvm[c0 + 1]; }
  float2 xv = *reinterpret_cast<const float2*>(xr + base);
  float s = o.x * (Wb[c0] + Wb[256 + c0]) + xv.x * (Wb[128 + c0] - Wb[256 + c0])
          + o.y * (Wb[c0 + 1] + Wb[256 + c0 + 1]) + xv.y * (Wb[128 + c0 + 1] - Wb[256 + c0 + 1]);
#pragma unroll
  for (int d = 1; d < 64; d <<= 1) s += __shfl_xor(s, d);
  float beta = 1.f / (1.f + __expf(-s));
  union { unsigned u; bf16 h[2]; } pk;
  pk.h[0] = __float2bfloat16(beta * xv.x + (1.f - beta) * o.x);
  pk.h[1] = __float2bfloat16(beta * xv.y + (1.f - beta) * o.y);
  *reinterpret_cast<unsigned*>(gated + base) = pk.u;
}

// ---------------- fused segment max-pool + prediction (batch_index sorted) ----------------
__global__ __launch_bounds__(256) void k_poolpred(const float* __restrict__ h,
    const int* __restrict__ batch, const float* __restrict__ predW,
    const float* __restrict__ predb, float* __restrict__ out) {
  __shared__ float cm[2][128];
  __shared__ int range[2];
  const int g = blockIdx.x, t = threadIdx.x;
  if (t < 2) {
    int target = g + t;
    int lo = 0, hi = N_;
    while (lo < hi) { int mid = (lo + hi) >> 1; if (batch[mid] < target) lo = mid + 1; else hi = mid; }
    range[t] = lo;
  }
  __syncthreads();
  const int lo = range[0], hi = range[1];
  const int c = t & 127, rg = t >> 7;
  float m = -3.402823466e+38f;
  for (int r = lo + rg; r < hi; r += 2) m = fmaxf(m, h[(size_t)r * H_ + c]);
  cm[rg][c] = m;
  __syncthreads();
  if (t < 64) {
    float m0 = fmaxf(cm[0][t], cm[1][t]);
    float m1 = fmaxf(cm[0][t + 64], cm[1][t + 64]);
    float s = m0 * predW[t] + m1 * predW[t + 64];
#pragma unroll
    for (int d = 1; d < 64; d <<= 1) s += __shfl_xor(s, d);
    if (t == 0) out[g] = s + predb[0];
  }
}

extern "C" void kernel_launch(void* const* d_in, const int* in_sizes, int n_in,
                              void* d_out, int out_size, void* d_ws, size_t ws_size,
                              hipStream_t stream) {
  const float* x      = (const float*)d_in[0];
  const int*   edge   = (const int*)d_in[1];
  const int*   esrc   = edge;
  const int*   edst   = edge + E_;
  const int*   batch  = (const int*)d_in[2];
  const float* embW   = (const float*)d_in[3];
  const float* embb   = (const float*)d_in[4];
  const float* emb_g  = (const float*)d_in[5];
  const float* emb_be = (const float*)d_in[6];
  const float* Wq     = (const float*)d_in[7];
  const float* bq     = (const float*)d_in[8];
  const float* Wk     = (const float*)d_in[9];
  const float* Wv     = (const float*)d_in[11];
  const float* bv     = (const float*)d_in[12];
  const float* Wskip  = (const float*)d_in[13];
  const float* bskip  = (const float*)d_in[14];
  const float* Wbeta  = (const float*)d_in[15];
  const float* W1     = (const float*)d_in[16];
  const float* b1     = (const float*)d_in[17];
  const float* g1     = (const float*)d_in[18];
  const float* be1    = (const float*)d_in[19];
  const float* W2     = (const float*)d_in[20];
  const float* b2     = (const float*)d_in[21];
  const float* predW  = (const float*)d_in[22];
  const float* predb  = (const float*)d_in[23];

  // ---- workspace layout (aliased lifetimes) ----
  float* ws = (float*)d_ws;
  size_t o = 0;
  auto alloc_f = [&](size_t n) { float* p = ws + o; o += n; return p; };
  float* A32   = alloc_f((size_t)N_ * 512);   // zf (GEMM1->attn) / t1 (FFN1->bn_apply)
  float* B32   = alloc_f((size_t)N_ * H_);    // out0 (Vproj->beta) / h32 (FFN2->pool)
  float* xr    = alloc_f((size_t)N_ * H_);
  float* stats = alloc_f((size_t)2 * 128 * DFF_);
  float* a_c   = alloc_f(DFF_);
  float* c_c   = alloc_f(DFF_);
  float* bcat  = alloc_f(5 * NF1_);
  float* bvm   = alloc_f(5 * 128);
  bf16* bp = (bf16*)(ws + o);
  size_t ob = 0;
  auto alloc_b = [&](size_t n) { bf16* p = bp + ob; ob += n; return p; };
  bf16* aggB = alloc_b((size_t)N_ * 512);     // also t1b (after Vproj)
  bf16* hb   = alloc_b((size_t)N_ * H_);
  bf16* gated= alloc_b((size_t)N_ * H_);
  bf16* Wcat1= alloc_b((size_t)5 * WCAT1SZ);
  bf16* W1t  = alloc_b((size_t)5 * W1TSZ);
  bf16* W2t  = alloc_b((size_t)5 * W2TSZ);
  bf16* Wvs  = alloc_b((size_t)5 * WVSSZ);
  int* deg    = (int*)(bp + ob);
  int* offs   = deg + N_;
  int* cursor = offs + N_ + 1;
  int* srcs   = cursor + N_;
  int* bsum   = srcs + E_;       // 64

  float* zf   = A32;  float* t1 = A32;
  float* out0 = B32;  float* h32 = B32;
  bf16*  t1b  = aggB;

  // ---- weight prep ----
  k_ptrans<<<TRBLKS + 15, 256, 0, stream>>>(Wskip, W1, W2, bskip, bv,
                                            Wcat1, W1t, W2t, bcat, bvm);
  k_wvprep<<<320, 256, 0, stream>>>(Wv, Wvs);
  k_gmat<<<dim3(20, 2), 256, 0, stream>>>(Wq, Wk, bq, Wcat1, bcat);

  // ---- CSR build ----
  hipMemsetAsync(deg, 0, N_ * sizeof(int), stream);
  hipMemsetAsync(cursor, 0, N_ * sizeof(int), stream);
  k_count  <<<E_ / 256, 256, 0, stream>>>(edst, deg);
  k_bsum   <<<64, 256, 0, stream>>>(deg, bsum);
  k_boffs  <<<64, 256, 0, stream>>>(deg, bsum, offs);
  k_scatter<<<E_ / 256, 256, 0, stream>>>(esrc, edst, offs, cursor, srcs);

  // ---- embedding (+fused stats) + BN + GELU -> bf16 ----
  k_embed2<<<128, 256, 0, stream>>>(x, embW, embb, A32, stats, stats + 128 * 128);
  k_bn_finalize<128, 128><<<1, 128, 0, stream>>>(stats, stats + 128 * 128, emb_g, emb_be, a_c, c_c);
  k_bn_apply_gelu_cast<128><<<N_ * H_ / 1024, 256, 0, stream>>>(A32, a_c, c_c, hb);

  for (int l = 0; l < L_; ++l) {
    const float* Wb_ = Wbeta + (size_t)l * 3 * H_;
    const float* b1_ = b1 + (size_t)l * DFF_;
    const float* g1_ = g1 + (size_t)l * DFF_;
    const float* be1_= be1 + (size_t)l * DFF_;
    const float* b2_ = b2 + (size_t)l * H_;

    // GEMM1: z | xr (block MFMA, K=128, NOUT=640)
    k_mfma<128, NF1_, 128, 2><<<dim3(N_ / 128, NF1_ / 128), 256, 0, stream>>>(
        hb, Wcat1 + (size_t)l * WCAT1SZ, bcat + (size_t)l * NF1_,
        nullptr, zf, xr, nullptr, nullptr);

    k_attn<<<N_ / 4, 256, 0, stream>>>(zf, hb, srcs, offs, aggB);

    // Vproj: out0 = aggB @ Wvs (LDS-resident-B skinny GEMM, no bias)
    k_sgemm<512, 128, 2, 5><<<dim3(N_ / 64, 2), 256, 0, stream>>>(
        aggB, Wvs + (size_t)l * WVSSZ, nullptr, out0, nullptr);

    k_beta<<<N_ / 4, 256, 0, stream>>>(out0, xr, Wb_, bvm + (size_t)l * 128, offs, gated);

    // FFN1: t1 = gated @ W1 + b1 (block MFMA) + BN partial stats
    k_mfma<128, 512, 128, 3><<<dim3(N_ / 128, 4), 256, 0, stream>>>(
        gated, W1t + (size_t)l * W1TSZ, b1_,
        t1, nullptr, nullptr, stats, stats + 128 * 512);

    k_bn_finalize<512, 128><<<4, 128, 0, stream>>>(
        stats, stats + 128 * 512, g1_, be1_, a_c, c_c);

    // BN+GELU+cast: t1 -> t1b (aliases aggB, dead after Vproj)
    k_bn_apply_gelu_cast<512><<<N_ * DFF_ / 1024, 256, 0, stream>>>(t1, a_c, c_c, t1b);

    // FFN2: h32/hb = t1b @ W2 + b2 (LDS-resident-B skinny GEMM)
    k_sgemm<512, 128, 2, 6><<<dim3(N_ / 64, 2), 256, 0, stream>>>(
        t1b, W2t + (size_t)l * W2TSZ, b2_, h32, hb);
  }

  // ---- fused pooling + prediction ----
  k_poolpred<<<G_, 256, 0, stream>>>(h32, batch, predW, predb, (float*)d_out);
}

// Round 19
// 671.386 us; speedup vs baseline: 1.5124x; 1.0214x over previous
//
#include <hip/hip_runtime.h>
#include <hip/hip_bf16.h>
#include <hip/hip_fp16.h>

using bf16 = __hip_bfloat16;
typedef __attribute__((ext_vector_type(8))) short bf16x8;
typedef __attribute__((ext_vector_type(4))) float f32x4;

constexpr int N_   = 16384;
constexpr int E_   = 262144;
constexpr int F_   = 16;
constexpr int H_   = 128;
constexpr int NF1_ = 640;    // z(512) | skip(128)
constexpr int DFF_ = 512;
constexpr int G_   = 128;
constexpr int L_   = 5;
constexpr float EPS_ = 1e-5f;

constexpr int WCAT1SZ = NF1_ * 128;    // 81920
constexpr int W1TSZ   = 512 * 128;
constexpr int W2TSZ   = 512 * 128;
constexpr int WVSSZ   = 128 * 512;     // Wvs: [128 n][512 k]
constexpr int TRBLKS  = 5 * 144;       // Ws:16 + W1:64 + W2:64 per layer

__device__ __forceinline__ float gelu_f(float x) {
  return 0.5f * x * (1.0f + erff(x * 0.70710678118654752440f));
}

__device__ __forceinline__ void unpack8(const uint4 w, float* f) {
  f[0] = __uint_as_float(w.x << 16); f[1] = __uint_as_float(w.x & 0xFFFF0000u);
  f[2] = __uint_as_float(w.y << 16); f[3] = __uint_as_float(w.y & 0xFFFF0000u);
  f[4] = __uint_as_float(w.z << 16); f[5] = __uint_as_float(w.z & 0xFFFF0000u);
  f[6] = __uint_as_float(w.w << 16); f[7] = __uint_as_float(w.w & 0xFFFF0000u);
}

// ---------------- weight prep: transposes (Ws,W1,W2) + bias tails ----------------
__global__ __launch_bounds__(256) void k_ptrans(
    const float* __restrict__ Ws, const float* __restrict__ W1,
    const float* __restrict__ W2, const float* __restrict__ bs,
    const float* __restrict__ bv,
    bf16* __restrict__ Wcat1, bf16* __restrict__ W1t, bf16* __restrict__ W2t,
    float* __restrict__ bcat, float* __restrict__ bvm) {
  __shared__ float lds[32][33];
  const int b = blockIdx.x;
  if (b >= TRBLKS) {                 // tails: bcat skip-cols + bvm
    int j = (b - TRBLKS) * 256 + threadIdx.x;
    if (j < 5 * NF1_) {
      int l = j / NF1_, c = j % NF1_;
      if (c >= 512) bcat[j] = bs[l * 128 + (c - 512)];
    } else if (j < 5 * NF1_ + 5 * 128) {
      int j2 = j - 5 * NF1_;
      int l = j2 / 128, n = j2 % 128;
      bvm[j2] = 0.25f * (bv[l * 512 + n] + bv[l * 512 + 128 + n]
                       + bv[l * 512 + 256 + n] + bv[l * 512 + 384 + n]);
    }
    return;
  }
  const int l = b / 144, t = b % 144;
  const float* src; int C; bf16* dst; int dld; int nof; int tt;
  if (t < 16) {         // Ws: [128][128] -> Wcat1 rows 512..639
    tt = t;
    src = Ws + (size_t)l * 128 * 128; C = 128;
    dst = Wcat1 + (size_t)l * WCAT1SZ; dld = 128; nof = 512;
  } else if (t < 80) {  // W1
    tt = t - 16;
    src = W1 + (size_t)l * 128 * 512; C = 512;
    dst = W1t + (size_t)l * W1TSZ; dld = 128; nof = 0;
  } else {              // W2
    tt = t - 80;
    src = W2 + (size_t)l * 512 * 128; C = 128;
    dst = W2t + (size_t)l * W2TSZ; dld = 512; nof = 0;
  }
  const int tpr = C >> 5;
  const int r0 = (tt / tpr) * 32, c0 = (tt % tpr) * 32;
  const int j = threadIdx.x & 31, g = threadIdx.x >> 5;
#pragma unroll
  for (int ii = 0; ii < 4; ++ii) {
    int i = g * 4 + ii;
    lds[i][j] = src[(size_t)(r0 + i) * C + c0 + j];
  }
  __syncthreads();
#pragma unroll
  for (int ii = 0; ii < 4; ++ii) {
    int i = g * 4 + ii;
    dst[(size_t)(nof + c0 + i) * dld + r0 + j] = __float2bfloat16(lds[j][i]);
  }
}

// ---------------- Wvs: per head, Wvs[n][h*128+c] = 0.25 * Wv[c][h*128+n] ----------------
__global__ __launch_bounds__(256) void k_wvprep(const float* __restrict__ Wv,
                                                bf16* __restrict__ Wvs) {
  __shared__ float lds[32][33];
  const int b = blockIdx.x;            // 5*4*16
  const int l = b / 64, rest = b % 64;
  const int h = rest / 16, tt = rest % 16;
  const int r0 = (tt / 4) * 32, c0 = (tt % 4) * 32;
  const float* src = Wv + (size_t)l * 128 * 512 + h * 128;
  bf16* dst = Wvs + (size_t)l * WVSSZ;
  const int j = threadIdx.x & 31, g = threadIdx.x >> 5;
#pragma unroll
  for (int ii = 0; ii < 4; ++ii) {
    int i = g * 4 + ii;
    lds[i][j] = src[(size_t)(r0 + i) * 512 + c0 + j];
  }
  __syncthreads();
#pragma unroll
  for (int ii = 0; ii < 4; ++ii) {
    int i = g * 4 + ii;
    dst[(size_t)(c0 + i) * 512 + h * 128 + r0 + j] = __float2bfloat16(0.25f * lds[j][i]);
  }
}

// ---------------- G = Wq_h @ Wk_h^T per (layer, head); writes GT rows + z-bias ----------------
__global__ __launch_bounds__(256) void k_gmat(
    const float* __restrict__ Wq, const float* __restrict__ Wk,
    const float* __restrict__ bq,
    bf16* __restrict__ Wcat1, float* __restrict__ bcat) {
  __shared__ float lq[32][132];
  __shared__ float lk[32][132];
  const int l = blockIdx.x >> 2, h = blockIdx.x & 3;
  const int half = blockIdx.y;
  const int tid = threadIdx.x;
  const int c = tid & 127, ch = tid >> 7;
  const int cp0 = half * 64 + ch * 32;
  const float* wqL = Wq + (size_t)l * 128 * 512 + h * 128;
  const float* wkL = Wk + (size_t)l * 128 * 512 + h * 128;
  float acc[32];
#pragma unroll
  for (int j = 0; j < 32; ++j) acc[j] = 0.f;
  for (int a0 = 0; a0 < 128; a0 += 32) {
    __syncthreads();
#pragma unroll
    for (int q4 = 0; q4 < 4; ++q4) {
      int f4 = tid * 4 + q4;
      int row = f4 >> 3, af = f4 & 7;
      float4 gq = *reinterpret_cast<const float4*>(wqL + (size_t)row * 512 + a0 + af * 4);
      float4 gk = *reinterpret_cast<const float4*>(wkL + (size_t)row * 512 + a0 + af * 4);
      lq[af * 4 + 0][row] = gq.x; lq[af * 4 + 1][row] = gq.y;
      lq[af * 4 + 2][row] = gq.z; lq[af * 4 + 3][row] = gq.w;
      lk[af * 4 + 0][row] = gk.x; lk[af * 4 + 1][row] = gk.y;
      lk[af * 4 + 2][row] = gk.z; lk[af * 4 + 3][row] = gk.w;
    }
    __syncthreads();
    for (int a = 0; a < 32; ++a) {
      float wq = lq[a][c];
#pragma unroll
      for (int j = 0; j < 32; ++j) acc[j] = fmaf(wq, lk[a][cp0 + j], acc[j]);
    }
  }
  bf16* gt = Wcat1 + (size_t)l * WCAT1SZ;
#pragma unroll
  for (int j = 0; j < 32; ++j)
    gt[(size_t)(h * 128 + cp0 + j) * 128 + c] = __float2bfloat16(acc[j]);
  if (half == 0 && ch == 0) {
    float s = 0.f;
    const float* wkr = wkL + (size_t)c * 512;
    const float* bqh = bq + (size_t)l * 512 + h * 128;
    for (int a = 0; a < 128; ++a) s = fmaf(wkr[a], bqh[a], s);
    bcat[(size_t)l * NF1_ + h * 128 + c] = s;
  }
}

// ---------------- embedding GEMM + fused BN partial stats ----------------
__global__ __launch_bounds__(256) void k_embed2(const float* __restrict__ x,
    const float* __restrict__ W, const float* __restrict__ b,
    float* __restrict__ out, float* __restrict__ ss, float* __restrict__ sq) {
  __shared__ float xs[128][16];
  __shared__ float wsm[16][128];
  __shared__ float sr[2][128], qr[2][128];
  const int blk = blockIdx.x;
  const int t = threadIdx.x;
  for (int i = t; i < 16 * 128; i += 256) wsm[i >> 7][i & 127] = W[i];
  for (int i = t; i < 128 * 16; i += 256) xs[i >> 4][i & 15] = x[(size_t)blk * 2048 + i];
  __syncthreads();
  const int c = t & 127, rg = t >> 7;
  float bc = b[c];
  float s = 0.f, q = 0.f;
  for (int r = rg * 64; r < rg * 64 + 64; ++r) {
    float v = bc;
#pragma unroll
    for (int f = 0; f < 16; ++f) v = fmaf(xs[r][f], wsm[f][c], v);
    out[(size_t)(blk * 128 + r) * 128 + c] = v;
    s += v; q += v * v;
  }
  sr[rg][c] = s; qr[rg][c] = q;
  __syncthreads();
  if (t < 128) { ss[blk * 128 + t] = sr[0][t] + sr[1][t]; sq[blk * 128 + t] = qr[0][t] + qr[1][t]; }
}

// ---------------- BatchNorm finalize / apply ----------------
template<int NC, int NP>
__global__ void k_bn_finalize(const float* __restrict__ sums, const float* __restrict__ sumsq,
                              const float* __restrict__ g, const float* __restrict__ be,
                              float* __restrict__ a, float* __restrict__ cc) {
  int c = blockIdx.x * 128 + threadIdx.x;
  if (c >= NC) return;
  float s = 0.f, q = 0.f;
  for (int b = 0; b < NP; ++b) { s += sums[(size_t)b * NC + c]; q += sumsq[(size_t)b * NC + c]; }
  float mean = s * (1.0f / N_);
  float var  = q * (1.0f / N_) - mean * mean;
  float inv  = rsqrtf(var + EPS_);
  float aa   = g[c] * inv;
  a[c]  = aa;
  cc[c] = be[c] - aa * mean;
}

template<int NC>
__global__ void k_bn_apply_gelu_cast(const float* __restrict__ xin, const float* __restrict__ a,
                                     const float* __restrict__ cc, bf16* __restrict__ outb) {
  int i4 = (blockIdx.x * 256 + threadIdx.x) * 4;
  int c = i4 & (NC - 1);
  float4 v = *reinterpret_cast<const float4*>(xin + i4);
  union { uint2 u2; bf16 h[4]; } pk;
  pk.h[0] = __float2bfloat16(gelu_f(fmaf(a[c + 0], v.x, cc[c + 0])));
  pk.h[1] = __float2bfloat16(gelu_f(fmaf(a[c + 1], v.y, cc[c + 1])));
  pk.h[2] = __float2bfloat16(gelu_f(fmaf(a[c + 2], v.z, cc[c + 2])));
  pk.h[3] = __float2bfloat16(gelu_f(fmaf(a[c + 3], v.w, cc[c + 3])));
  *reinterpret_cast<uint2*>(outb + i4) = pk.u2;
}

// ---------------- CSR build over dst ----------------
__global__ void k_count(const int* __restrict__ dst, int* __restrict__ deg) {
  int e = blockIdx.x * 256 + threadIdx.x;
  if (e < E_) atomicAdd(&deg[dst[e]], 1);
}

__global__ void k_bsum(const int* __restrict__ deg, int* __restrict__ bsum) {
  __shared__ int sh[256];
  int t = threadIdx.x;
  sh[t] = deg[blockIdx.x * 256 + t];
  __syncthreads();
  for (int d = 128; d > 0; d >>= 1) { if (t < d) sh[t] += sh[t + d]; __syncthreads(); }
  if (t == 0) bsum[blockIdx.x] = sh[0];
}

__global__ void k_boffs(const int* __restrict__ deg, const int* __restrict__ bsum,
                        int* __restrict__ offs) {
  __shared__ int sh[256];
  __shared__ int baseSh;
  int t = threadIdx.x;
  if (t < 64) {
    int v = bsum[t];
    int s = v;
    for (int d = 1; d < 64; d <<= 1) { int o = __shfl_up(s, d); if (t >= d) s += o; }
    if (t == (int)blockIdx.x) baseSh = s - v;
  }
  int v = deg[blockIdx.x * 256 + t];
  sh[t] = v;
  __syncthreads();
  for (int d = 1; d < 256; d <<= 1) {
    int add = (t >= d) ? sh[t - d] : 0;
    __syncthreads();
    sh[t] += add;
    __syncthreads();
  }
  offs[blockIdx.x * 256 + t] = baseSh + sh[t] - v;
  if (blockIdx.x == 63 && t == 255) offs[N_] = E_;
}

__global__ void k_scatter(const int* __restrict__ src, const int* __restrict__ dst,
                          const int* __restrict__ off, int* __restrict__ cursor,
                          int* __restrict__ srcs) {
  int e = blockIdx.x * 256 + threadIdx.x;
  if (e < E_) {
    int d = dst[e];
    int pos = off[d] + atomicAdd(&cursor[d], 1);
    srcs[pos] = src[e];
  }
}

// ---------------- block MFMA GEMM (K=128) ----------------
// MODE 2: NOUT=640: route z fp16 (cols<512) / xr fp32; +bias. grid (N/128, 5)
// MODE 3: NOUT=512: fp32 out + per-m-tile BN column partials; +bias. grid (N/128, 4)
template<int KDIM, int NOUT, int TM, int MODE>
__global__ __launch_bounds__(256) void k_mfma(
    const bf16* __restrict__ A, const bf16* __restrict__ BT,
    const float* __restrict__ bias,
    float* __restrict__ outF,
    __half* __restrict__ zfp, float* __restrict__ xrp,
    float* __restrict__ ss, float* __restrict__ sq) {
  constexpr int MF = TM / 32;
  __shared__ bf16 As[TM][72];
  __shared__ bf16 Bs[128][72];
  __shared__ float sred[2][128], qred[2][128];
  const int tid = threadIdx.x;
  const int wid = tid >> 6, lane = tid & 63;
  const int wr = wid >> 1, wc = wid & 1;
  const int m0 = blockIdx.x * TM, n0 = blockIdx.y * 128;
  const int ln = lane & 15, lq = lane >> 4;
  f32x4 acc[MF][4];
#pragma unroll
  for (int i = 0; i < MF; ++i)
#pragma unroll
    for (int j = 0; j < 4; ++j) acc[i][j] = (f32x4){0.f, 0.f, 0.f, 0.f};

  for (int k0 = 0; k0 < KDIM; k0 += 64) {
#pragma unroll
    for (int u = tid; u < TM * 8; u += 256) {
      int r = u >> 3, c = u & 7;
      *(uint4*)(&As[r][c * 8]) = *(const uint4*)(A + (size_t)(m0 + r) * KDIM + k0 + c * 8);
    }
#pragma unroll
    for (int u = tid; u < 1024; u += 256) {
      int r = u >> 3, c = u & 7;
      *(uint4*)(&Bs[r][c * 8]) = *(const uint4*)(BT + (size_t)(n0 + r) * KDIM + k0 + c * 8);
    }
    __syncthreads();
#pragma unroll
    for (int kk = 0; kk < 2; ++kk) {
      bf16x8 af[MF], bg[4];
#pragma unroll
      for (int i = 0; i < MF; ++i)
        af[i] = *(const bf16x8*)(&As[wr * (TM / 2) + i * 16 + ln][kk * 32 + lq * 8]);
#pragma unroll
      for (int j = 0; j < 4; ++j)
        bg[j] = *(const bf16x8*)(&Bs[wc * 64 + j * 16 + ln][kk * 32 + lq * 8]);
#pragma unroll
      for (int i = 0; i < MF; ++i)
#pragma unroll
        for (int j = 0; j < 4; ++j)
          acc[i][j] = __builtin_amdgcn_mfma_f32_16x16x32_bf16(af[i], bg[j], acc[i][j], 0, 0, 0);
    }
    __syncthreads();
  }
  float ssj[4] = {0.f, 0.f, 0.f, 0.f}, sqj[4] = {0.f, 0.f, 0.f, 0.f};
#pragma unroll
  for (int i = 0; i < MF; ++i) {
#pragma unroll
    for (int j = 0; j < 4; ++j) {
      int gcol = n0 + wc * 64 + j * 16 + ln;
      float bv = bias[gcol];
      int row0 = m0 + wr * (TM / 2) + i * 16 + lq * 4;
#pragma unroll
      for (int qq = 0; qq < 4; ++qq) {
        float val = acc[i][j][qq] + bv;
        int row = row0 + qq;
        if (MODE == 3) {
          outF[(size_t)row * NOUT + gcol] = val;
          ssj[j] += val; sqj[j] += val * val;
        } else {
          if (gcol < 512) zfp[(size_t)row * 512 + gcol] = __float2half(val);
          else            xrp[(size_t)row * H_ + (gcol - 512)] = val;
        }
      }
    }
  }
  if constexpr (MODE == 3) {
#pragma unroll
    for (int j = 0; j < 4; ++j) {
      ssj[j] += __shfl_xor(ssj[j], 16); ssj[j] += __shfl_xor(ssj[j], 32);
      sqj[j] += __shfl_xor(sqj[j], 16); sqj[j] += __shfl_xor(sqj[j], 32);
    }
    if (lq == 0) {
#pragma unroll
      for (int j = 0; j < 4; ++j) {
        sred[wr][wc * 64 + j * 16 + ln] = ssj[j];
        qred[wr][wc * 64 + j * 16 + ln] = sqj[j];
      }
    }
    __syncthreads();
    if (tid < 128) {
      ss[(size_t)blockIdx.x * NOUT + n0 + tid] = sred[0][tid] + sred[1][tid];
      sq[(size_t)blockIdx.x * NOUT + n0 + tid] = qred[0][tid] + qred[1][tid];
    }
  }
}

// ---------------- skinny GEMM: B resident in LDS (fragment-major), barrier-free main loop ----
// C[M,128] = A[M,512] @ BT[128,512]^T. grid (N/64, 2): blockIdx.y = column half.
// MODE 5: fp32 out, no bias. MODE 6: fp32 + bf16 out, +bias.
template<int KDIM, int NOUT, int CSPL, int MODE>
__global__ __launch_bounds__(256) void k_sgemm(
    const bf16* __restrict__ A, const bf16* __restrict__ BT,
    const float* __restrict__ bias,
    float* __restrict__ outF, bf16* __restrict__ outB) {
  constexpr int KS = KDIM / 32;            // 16
  constexpr int NCOL = NOUT / CSPL;        // 64
  constexpr int NFR = NCOL / 16;           // 4
  __shared__ bf16 Bs[NFR][KS][64][8];      // 64 KB, ds_read linear across lanes
  const int tid = threadIdx.x;
  const int wid = tid >> 6, lane = tid & 63;
  const int ln = lane & 15, lq = lane >> 4;
  const int nc0 = blockIdx.y * NCOL;
  for (int idx = tid; idx < NCOL * (KDIM / 8); idx += 256) {
    int col = idx / (KDIM / 8);
    int oct = idx % (KDIM / 8);
    uint4 w = *(const uint4*)(BT + (size_t)(nc0 + col) * KDIM + oct * 8);
    int ks = oct >> 2, q = oct & 3;
    *(uint4*)(&Bs[col >> 4][ks][q * 16 + (col & 15)][0]) = w;
  }
  __syncthreads();
  const int m0 = blockIdx.x * 64 + wid * 16;
  bf16x8 a[KS];
  const bf16* ap = A + (size_t)(m0 + ln) * KDIM + lq * 8;
#pragma unroll
  for (int ks = 0; ks < KS; ++ks) a[ks] = *(const bf16x8*)(ap + ks * 32);
  const int orow = m0 + lq * 4;
#pragma unroll
  for (int nf = 0; nf < NFR; ++nf) {
    f32x4 acc0 = (f32x4){0.f, 0.f, 0.f, 0.f};
    f32x4 acc1 = (f32x4){0.f, 0.f, 0.f, 0.f};
#pragma unroll
    for (int ks = 0; ks < KS; ks += 2) {   // two chains -> 2x MFMA ILP
      acc0 = __builtin_amdgcn_mfma_f32_16x16x32_bf16(a[ks],     *(const bf16x8*)(&Bs[nf][ks][lane][0]),     acc0, 0, 0, 0);
      acc1 = __builtin_amdgcn_mfma_f32_16x16x32_bf16(a[ks + 1], *(const bf16x8*)(&Bs[nf][ks + 1][lane][0]), acc1, 0, 0, 0);
    }
    const int col = nc0 + nf * 16 + ln;
    float bv = 0.f;
    if constexpr (MODE == 6) bv = bias[col];
    float v0 = (acc0[0] + acc1[0]) + bv;
    float v1 = (acc0[1] + acc1[1]) + bv;
    float v2 = (acc0[2] + acc1[2]) + bv;
    float v3 = (acc0[3] + acc1[3]) + bv;
    outF[(size_t)(orow + 0) * NOUT + col] = v0;
    outF[(size_t)(orow + 1) * NOUT + col] = v1;
    outF[(size_t)(orow + 2) * NOUT + col] = v2;
    outF[(size_t)(orow + 3) * NOUT + col] = v3;
    if constexpr (MODE == 6) {
      outB[(size_t)(orow + 0) * NOUT + col] = __float2bfloat16(v0);
      outB[(size_t)(orow + 1) * NOUT + col] = __float2bfloat16(v1);
      outB[(size_t)(orow + 2) * NOUT + col] = __float2bfloat16(v2);
      outB[(size_t)(orow + 3) * NOUT + col] = __float2bfloat16(v3);
    }
  }
}

// ---------------- attention: gather hb only; aggregate hb into per-head agg ----------------
__global__ __launch_bounds__(256) void k_attn(const __half* __restrict__ zf,
    const bf16* __restrict__ hb, const int* __restrict__ srcs,
    const int* __restrict__ off, bf16* __restrict__ aggB) {
  const int wave = threadIdx.x >> 6;
  const int lane = threadIdx.x & 63;
  const int bid = blockIdx.x;                      // 4096 blocks
  const int swz = ((bid & 7) << 9) | (bid >> 3);   // XCD-contiguous chunks
  const int node = swz * 4 + wave;
  const int sub = lane & 15;
  const float scale = 0.08838834764831845f;        // 1/sqrt(128)
  float qf[8];
  {
    uint4 qw = *reinterpret_cast<const uint4*>(zf + (size_t)node * 512 + lane * 8);
    const __half2* qh = reinterpret_cast<const __half2*>(&qw);
    float2 a = __half22float2(qh[0]), b = __half22float2(qh[1]);
    float2 c = __half22float2(qh[2]), d = __half22float2(qh[3]);
    qf[0]=a.x; qf[1]=a.y; qf[2]=b.x; qf[3]=b.y;
    qf[4]=c.x; qf[5]=c.y; qf[6]=d.x; qf[7]=d.y;
  }
  float m = -1e30f, den = 0.f;
  float acc[8] = {0.f, 0.f, 0.f, 0.f, 0.f, 0.f, 0.f, 0.f};
  const int s0 = off[node], s1 = off[node + 1];
  if (s0 < s1) {
    int i0 = srcs[s0];
    int i1 = (s0 + 1 < s1) ? srcs[s0 + 1] : i0;
    uint4 h0 = *(const uint4*)(hb + (size_t)i0 * 128 + sub * 8);
    uint4 h1 = *(const uint4*)(hb + (size_t)i1 * 128 + sub * 8);
    for (int t = s0; t < s1; t += 2) {
      int j0 = (t + 2 < s1) ? srcs[t + 2] : i0;
      int j1 = (t + 3 < s1) ? srcs[t + 3] : i0;
      uint4 nh0 = *(const uint4*)(hb + (size_t)j0 * 128 + sub * 8);
      uint4 nh1 = *(const uint4*)(hb + (size_t)j1 * 128 + sub * 8);
      {
        float hf[8]; unpack8(h0, hf);
        float p = hf[0]*qf[0]+hf[1]*qf[1]+hf[2]*qf[2]+hf[3]*qf[3]
                + hf[4]*qf[4]+hf[5]*qf[5]+hf[6]*qf[6]+hf[7]*qf[7];
        p += __shfl_xor(p, 1); p += __shfl_xor(p, 2);
        p += __shfl_xor(p, 4); p += __shfl_xor(p, 8);
        float logit = p * scale;
        if (logit > m + 8.f) {
          float co = __expf(m - logit);
          den *= co;
#pragma unroll
          for (int j = 0; j < 8; ++j) acc[j] *= co;
          m = logit;
        }
        float pe = __expf(logit - m);
        den += pe;
#pragma unroll
        for (int j = 0; j < 8; ++j) acc[j] = fmaf(pe, hf[j], acc[j]);
      }
      if (t + 1 < s1) {
        float hf[8]; unpack8(h1, hf);
        float p = hf[0]*qf[0]+hf[1]*qf[1]+hf[2]*qf[2]+hf[3]*qf[3]
                + hf[4]*qf[4]+hf[5]*qf[5]+hf[6]*qf[6]+hf[7]*qf[7];
        p += __shfl_xor(p, 1); p += __shfl_xor(p, 2);
        p += __shfl_xor(p, 4); p += __shfl_xor(p, 8);
        float logit = p * scale;
        if (logit > m + 8.f) {
          float co = __expf(m - logit);
          den *= co;
#pragma unroll
          for (int j = 0; j < 8; ++j) acc[j] *= co;
          m = logit;
        }
        float pe = __expf(logit - m);
        den += pe;
#pragma unroll
        for (int j = 0; j < 8; ++j) acc[j] = fmaf(pe, hf[j], acc[j]);
      }
      h0 = nh0; h1 = nh1;
    }
  }
  float inv = 1.f / (den + 1e-16f);
  union { uint4 u4; bf16 h[8]; } pk;
#pragma unroll
  for (int j = 0; j < 8; ++j) pk.h[j] = __float2bfloat16(acc[j] * inv);
  *reinterpret_cast<uint4*>(aggB + (size_t)node * 512 + lane * 8) = pk.u4;
}

// ---------------- beta gate: out = out0 + bvm (if deg>0); gated = beta*xr + (1-beta)*out ----------------
__global__ __launch_bounds__(256) void k_beta(const float* __restrict__ out0,
    const float* __restrict__ xr, const float* __restrict__ Wb,
    const float* __restrict__ bvm, const int* __restrict__ off,
    bf16* __restrict__ gated) {
  const int wave = threadIdx.x >> 6;
  const int lane = threadIdx.x & 63;
  const int node = blockIdx.x * 4 + wave;
  const int c0 = lane * 2;
  bool hasE = off[node + 1] > off[node];
  const size_t base = (size_t)node * H_ + c0;
  float2 o = *reinterpret_cast<const float2*>(out0 + base);
  if (hasE) { o.x += bvm[c0]; o.y += bvm[c0 + 1]; }
  float2 xv = *reinterpret_cast<const float2*>(xr + base);
  float s = o.x * (Wb[c0] + Wb[256 + c0]) + xv.x * (Wb[128 + c0] - Wb[256 + c0])
          + o.y * (Wb[c0 + 1] + Wb[256 + c0 + 1]) + xv.y * (Wb[128 + c0 + 1] - Wb[256 + c0 + 1]);
#pragma unroll
  for (int d = 1; d < 64; d <<= 1) s += __shfl_xor(s, d);
  float beta = 1.f / (1.f + __expf(-s));
  union { unsigned u; bf16 h[2]; } pk;
  pk.h[0] = __float2bfloat16(beta * xv.x + (1.f - beta) * o.x);
  pk.h[1] = __float2bfloat16(beta * xv.y + (1.f - beta) * o.y);
  *reinterpret_cast<unsigned*>(gated + base) = pk.u;
}

// ---------------- fused segment max-pool + prediction (batch_index sorted) ----------------
__global__ __launch_bounds__(256) void k_poolpred(const float* __restrict__ h,
    const int* __restrict__ batch, const float* __restrict__ predW,
    const float* __restrict__ predb, float* __restrict__ out) {
  __shared__ float cm[2][128];
  __shared__ int range[2];
  const int g = blockIdx.x, t = threadIdx.x;
  if (t < 2) {
    int target = g + t;
    int lo = 0, hi = N_;
    while (lo < hi) { int mid = (lo + hi) >> 1; if (batch[mid] < target) lo = mid + 1; else hi = mid; }
    range[t] = lo;
  }
  __syncthreads();
  const int lo = range[0], hi = range[1];
  const int c = t & 127, rg = t >> 7;
  float m = -3.402823466e+38f;
  for (int r = lo + rg; r < hi; r += 2) m = fmaxf(m, h[(size_t)r * H_ + c]);
  cm[rg][c] = m;
  __syncthreads();
  if (t < 64) {
    float m0 = fmaxf(cm[0][t], cm[1][t]);
    float m1 = fmaxf(cm[0][t + 64], cm[1][t + 64]);
    float s = m0 * predW[t] + m1 * predW[t + 64];
#pragma unroll
    for (int d = 1; d < 64; d <<= 1) s += __shfl_xor(s, d);
    if (t == 0) out[g] = s + predb[0];
  }
}

extern "C" void kernel_launch(void* const* d_in, const int* in_sizes, int n_in,
                              void* d_out, int out_size, void* d_ws, size_t ws_size,
                              hipStream_t stream) {
  const float* x      = (const float*)d_in[0];
  const int*   edge   = (const int*)d_in[1];
  const int*   esrc   = edge;
  const int*   edst   = edge + E_;
  const int*   batch  = (const int*)d_in[2];
  const float* embW   = (const float*)d_in[3];
  const float* embb   = (const float*)d_in[4];
  const float* emb_g  = (const float*)d_in[5];
  const float* emb_be = (const float*)d_in[6];
  const float* Wq     = (const float*)d_in[7];
  const float* bq     = (const float*)d_in[8];
  const float* Wk     = (const float*)d_in[9];
  const float* Wv     = (const float*)d_in[11];
  const float* bv     = (const float*)d_in[12];
  const float* Wskip  = (const float*)d_in[13];
  const float* bskip  = (const float*)d_in[14];
  const float* Wbeta  = (const float*)d_in[15];
  const float* W1     = (const float*)d_in[16];
  const float* b1     = (const float*)d_in[17];
  const float* g1     = (const float*)d_in[18];
  const float* be1    = (const float*)d_in[19];
  const float* W2     = (const float*)d_in[20];
  const float* b2     = (const float*)d_in[21];
  const float* predW  = (const float*)d_in[22];
  const float* predb  = (const float*)d_in[23];

  // ---- workspace layout (aliased lifetimes) ----
  float* ws = (float*)d_ws;
  size_t o = 0;
  auto alloc_f = [&](size_t n) { float* p = ws + o; o += n; return p; };
  float* A32   = alloc_f((size_t)N_ * 512);   // embed out / zf(fp16) / t1(fp32)
  float* B32   = alloc_f((size_t)N_ * H_);    // out0 (Vproj->beta) / h32 (FFN2->pool)
  float* xr    = alloc_f((size_t)N_ * H_);
  float* stats = alloc_f((size_t)2 * 128 * DFF_);
  float* a_c   = alloc_f(DFF_);
  float* c_c   = alloc_f(DFF_);
  float* bcat  = alloc_f(5 * NF1_);
  float* bvm   = alloc_f(5 * 128);
  bf16* bp = (bf16*)(ws + o);
  size_t ob = 0;
  auto alloc_b = [&](size_t n) { bf16* p = bp + ob; ob += n; return p; };
  bf16* aggB = alloc_b((size_t)N_ * 512);     // also t1b (after Vproj)
  bf16* hb   = alloc_b((size_t)N_ * H_);
  bf16* gated= alloc_b((size_t)N_ * H_);
  bf16* Wcat1= alloc_b((size_t)5 * WCAT1SZ);
  bf16* W1t  = alloc_b((size_t)5 * W1TSZ);
  bf16* W2t  = alloc_b((size_t)5 * W2TSZ);
  bf16* Wvs  = alloc_b((size_t)5 * WVSSZ);
  int* deg    = (int*)(bp + ob);
  int* offs   = deg + N_;
  int* cursor = offs + N_ + 1;
  int* srcs   = cursor + N_;
  int* bsum   = srcs + E_;       // 64

  __half* zf  = (__half*)A32;
  float*  t1  = A32;
  float* out0 = B32;  float* h32 = B32;
  bf16*  t1b  = aggB;

  // ---- weight prep ----
  k_ptrans<<<TRBLKS + 15, 256, 0, stream>>>(Wskip, W1, W2, bskip, bv,
                                            Wcat1, W1t, W2t, bcat, bvm);
  k_wvprep<<<320, 256, 0, stream>>>(Wv, Wvs);
  k_gmat<<<dim3(20, 2), 256, 0, stream>>>(Wq, Wk, bq, Wcat1, bcat);

  // ---- CSR build ----
  hipMemsetAsync(deg, 0, N_ * sizeof(int), stream);
  hipMemsetAsync(cursor, 0, N_ * sizeof(int), stream);
  k_count  <<<E_ / 256, 256, 0, stream>>>(edst, deg);
  k_bsum   <<<64, 256, 0, stream>>>(deg, bsum);
  k_boffs  <<<64, 256, 0, stream>>>(deg, bsum, offs);
  k_scatter<<<E_ / 256, 256, 0, stream>>>(esrc, edst, offs, cursor, srcs);

  // ---- embedding (+fused stats) + BN + GELU -> bf16 ----
  k_embed2<<<128, 256, 0, stream>>>(x, embW, embb, A32, stats, stats + 128 * 128);
  k_bn_finalize<128, 128><<<1, 128, 0, stream>>>(stats, stats + 128 * 128, emb_g, emb_be, a_c, c_c);
  k_bn_apply_gelu_cast<128><<<N_ * H_ / 1024, 256, 0, stream>>>(A32, a_c, c_c, hb);

  for (int l = 0; l < L_; ++l) {
    const float* Wb_ = Wbeta + (size_t)l * 3 * H_;
    const float* b1_ = b1 + (size_t)l * DFF_;
    const float* g1_ = g1 + (size_t)l * DFF_;
    const float* be1_= be1 + (size_t)l * DFF_;
    const float* b2_ = b2 + (size_t)l * H_;

    // GEMM1: z(fp16) | xr(fp32) (block MFMA, K=128, NOUT=640)
    k_mfma<128, NF1_, 128, 2><<<dim3(N_ / 128, NF1_ / 128), 256, 0, stream>>>(
        hb, Wcat1 + (size_t)l * WCAT1SZ, bcat + (size_t)l * NF1_,
        nullptr, zf, xr, nullptr, nullptr);

    k_attn<<<N_ / 4, 256, 0, stream>>>(zf, hb, srcs, offs, aggB);

    // Vproj: out0 = aggB @ Wvs (LDS-resident-B skinny GEMM, no bias)
    k_sgemm<512, 128, 2, 5><<<dim3(N_ / 64, 2), 256, 0, stream>>>(
        aggB, Wvs + (size_t)l * WVSSZ, nullptr, out0, nullptr);

    k_beta<<<N_ / 4, 256, 0, stream>>>(out0, xr, Wb_, bvm + (size_t)l * 128, offs, gated);

    // FFN1: t1(fp32) = gated @ W1 + b1 (block MFMA) + BN partial stats
    k_mfma<128, 512, 128, 3><<<dim3(N_ / 128, 4), 256, 0, stream>>>(
        gated, W1t + (size_t)l * W1TSZ, b1_,
        t1, nullptr, nullptr, stats, stats + 128 * 512);

    k_bn_finalize<512, 128><<<4, 128, 0, stream>>>(
        stats, stats + 128 * 512, g1_, be1_, a_c, c_c);

    // BN+GELU+cast: t1(fp32) -> t1b (aliases aggB, dead after Vproj)
    k_bn_apply_gelu_cast<512><<<N_ * DFF_ / 1024, 256, 0, stream>>>(t1, a_c, c_c, t1b);

    // FFN2: h32/hb = t1b @ W2 + b2 (LDS-resident-B skinny GEMM)
    k_sgemm<512, 128, 2, 6><<<dim3(N_ / 64, 2), 256, 0, stream>>>(
        t1b, W2t + (size_t)l * W2TSZ, b2_, h32, hb);
  }

  // ---- fused pooling + prediction ----
  k_poolpred<<<G_, 256, 0, stream>>>(h32, batch, predW, predb, (float*)d_out);
}